// Round 11
// baseline (1378.795 us; speedup 1.0000x reference)
//
#include <hip/hip_runtime.h>
#include <hip/hip_bf16.h>

typedef __attribute__((ext_vector_type(8))) short short8;
typedef __attribute__((ext_vector_type(4))) float floatx4;
typedef unsigned short u16;
typedef unsigned int u32;

#define T_TOK 131072   // 8 * 128 * 128 tokens
#define LN_EPS 1e-5f
#define ATTN_SCALE 0.08838834764831845f   // 1/sqrt(128)

__device__ __forceinline__ u16 f2b(float f){
  __hip_bfloat16 h = __float2bfloat16(f);
  return *reinterpret_cast<u16*>(&h);
}
__device__ __forceinline__ float blo(u32 u){ union{u32 i; float f;} c; c.i = u<<16; return c.f; }
__device__ __forceinline__ float bhi(u32 u){ union{u32 i; float f;} c; c.i = u & 0xffff0000u; return c.f; }
__device__ __forceinline__ u32 pk2(float lo, float hi){
  return (u32)f2b(lo) | ((u32)f2b(hi)<<16);
}
// Branchless gelu: erf(v/sqrt2) via Abramowitz-Stegun 7.1.26 (max err 1.5e-7,
// far below the bf16 quantization applied right after). ~15 VALU ops.
__device__ __forceinline__ float gelu_f(float v){
  float xs = v * 0.70710678118654752f;
  float ax = fabsf(xs);
  float t = __builtin_amdgcn_rcpf(fmaf(0.3275911f, ax, 1.0f));
  float p = t*fmaf(t, fmaf(t, fmaf(t, fmaf(t, 1.061405429f, -1.453152027f),
                                   1.421413741f), -0.284496736f), 0.254829592f);
  float e = __expf(-ax*ax);
  float er = fmaf(-p, e, 1.0f);
  er = copysignf(er, v);
  return 0.5f*v*(1.0f + er);
}

// ---------------------------------------------------------------------------
// NCHW f32 -> [T,64] bf16 transpose
// ---------------------------------------------------------------------------
__global__ __launch_bounds__(256) void trans_k(
    const float* __restrict__ dct, u16* __restrict__ dctT)
{
  __shared__ u16 tl[256][66];
  int tid = threadIdx.x;
  int p = blockIdx.x*256 + tid;
  int n = p >> 14;
  int r = p & 16383;
  const float* dctn = dct + (long)n*64*16384;
  #pragma unroll
  for (int c=0;c<64;c++) tl[tid][c] = f2b(dctn[c*16384 + r]);
  __syncthreads();
  long base = (long)blockIdx.x*256*64;
  for (int pass=0; pass<64; pass++){
    int idx = pass*256 + tid;
    int pp = idx>>6, o = idx&63;
    dctT[base + idx] = tl[pp][o];
  }
}

// ---------------------------------------------------------------------------
// Encoder conv as MFMA GEMM, v2. Block = one image row (128 px) x 64 out ch.
// Halo rows staged once in XOR-swizzled LDS; weights prepacked fragment-order.
// ---------------------------------------------------------------------------
__global__ __launch_bounds__(256) void convgemm_k(
    const u16* __restrict__ dctT, const uint4* __restrict__ cwB,
    const float* __restrict__ c1b, const float* __restrict__ qt,
    u16* __restrict__ tbuf)
{
  __shared__ uint4 AL[3120];   // [3 rows][130 pxs][8 slots], slot = k8 ^ (pxs&7)
  int tid = threadIdx.x, wave = tid>>6, lane = tid&63;
  int l15 = lane & 15, quad = lane >> 4;
  int bm = blockIdx.x*128;
  int n = bm >> 14;
  int yb = (bm & 16383) >> 7;
  int wm = wave*32;
  for (int i = tid; i < 3120; i += 256){
    int row = i / 1040;
    int rem = i - row*1040;
    int pxs = rem >> 3;
    int k8 = rem & 7;
    int grow = yb + row - 1;
    int gpx = pxs - 1;
    uint4 v = {0,0,0,0};
    if (((unsigned)grow < 128u) && ((unsigned)gpx < 128u))
      v = *reinterpret_cast<const uint4*>(dctT + ((long)bm + (row-1)*128 + gpx)*64 + k8*8);
    AL[row*1040 + (pxs<<3) + (k8 ^ (pxs&7))] = v;
  }
  float qv[4], bi4[4];
  #pragma unroll
  for (int nt=0; nt<4; nt++){
    int col = nt*16 + l15;
    bi4[nt] = c1b[col];
    qv[nt] = qt[n*64 + col];
  }
  uint4 bcur[8];
  #pragma unroll
  for (int i=0;i<8;i++) bcur[i] = cwB[i*64 + lane];

  floatx4 acc[2][4];
  #pragma unroll
  for (int i=0;i<2;i++)
    #pragma unroll
    for (int j=0;j<4;j++)
      #pragma unroll
      for (int e=0;e<4;e++) acc[i][j][e]=0.f;

  __syncthreads();

  #pragma unroll
  for (int tap=0; tap<9; tap++){
    int dy = tap/3 - 1, dx = tap%3 - 1;
    uint4 bnx[8];
    if (tap < 8){
      #pragma unroll
      for (int i=0;i<8;i++) bnx[i] = cwB[(tap+1)*512 + i*64 + lane];
    }
    short8 af[2][2];
    #pragma unroll
    for (int mt=0; mt<2; mt++)
      #pragma unroll
      for (int ks=0; ks<2; ks++){
        int pxs = wm + mt*16 + l15 + dx + 1;
        int k8 = ks*4 + quad;
        af[mt][ks] = *reinterpret_cast<const short8*>(
            &AL[(dy+1)*1040 + (pxs<<3) + (k8 ^ (pxs&7))]);
      }
    #pragma unroll
    for (int ks=0; ks<2; ks++)
      #pragma unroll
      for (int mt=0; mt<2; mt++)
        #pragma unroll
        for (int nt=0; nt<4; nt++)
          acc[mt][nt] = __builtin_amdgcn_mfma_f32_16x16x32_bf16(
              af[mt][ks],
              *reinterpret_cast<const short8*>(&bcur[nt*2+ks]),
              acc[mt][nt], 0,0,0);
    #pragma unroll
    for (int i=0;i<8;i++) bcur[i] = bnx[i];
  }
  const u16* ALu = (const u16*)AL;
  #pragma unroll
  for (int mt=0; mt<2; mt++){
    #pragma unroll
    for (int nt=0; nt<4; nt++){
      int col = nt*16 + l15;
      int k8c = col>>3, sub = col&7;
      #pragma unroll
      for (int rr2=0; rr2<4; rr2++){
        int p = wm + mt*16 + quad*4 + rr2;
        int pxs = p + 1;
        float cen = blo((u32)ALu[(((130 + pxs)<<3) + (k8c ^ (pxs&7)))*8 + sub]);
        float val = acc[mt][nt][rr2] + bi4[nt];
        tbuf[((long)bm + p)*64 + col] = f2b(cen + qv[nt]*val);
      }
    }
  }
}

// ---------------------------------------------------------------------------
// Weight prepack: qkv/ff1/ff2 -> bf16 [n][k]; qkv bias concat (f32);
// conv weights -> bf16 fragment-order [tap][512 uint4-slots].
// ---------------------------------------------------------------------------
__global__ __launch_bounds__(256) void prep_k(
    const float* __restrict__ qw, const float* __restrict__ kw,
    const float* __restrict__ vw, const float* __restrict__ qb2,
    const float* __restrict__ kb2, const float* __restrict__ vb2,
    const float* __restrict__ f1, const float* __restrict__ f2,
    const float* __restrict__ c1w,
    u16* __restrict__ qkvB, u16* __restrict__ ff1B,
    u16* __restrict__ ff2B, float* __restrict__ biasB,
    uint4* __restrict__ cwB)
{
  int idx = blockIdx.x*256 + threadIdx.x;
  if (idx < 196608){
    int l = idx / 49152, r = idx % 49152;
    int sel = r / 16384, rr = r % 16384;
    int k = rr >> 7, nn = rr & 127;
    const float* src = (sel==0? qw : sel==1? kw : vw) + l*16384 + rr;
    qkvB[(size_t)l*49152 + (size_t)(sel*128 + nn)*128 + k] = f2b(*src);
  } else if (idx < 458752){
    int e = idx - 196608; int l = e >> 16, r = e & 65535;
    int k = r >> 9, nn = r & 511;
    ff1B[(size_t)l*65536 + (size_t)nn*128 + k] = f2b(f1[(size_t)l*65536 + r]);
  } else if (idx < 720896){
    int e = idx - 458752; int l = e >> 16, r = e & 65535;
    int k = r >> 7, nn = r & 127;
    ff2B[(size_t)l*65536 + (size_t)nn*512 + k] = f2b(f2[(size_t)l*65536 + r]);
  } else if (idx < 722432){
    int e = idx - 720896;       // [4][384]
    int l = e / 384, c = e % 384;
    int sel = c >> 7, nn = c & 127;
    const float* src = (sel==0? qb2 : sel==1? kb2 : vb2) + l*128 + nn;
    biasB[e] = *src;
  } else if (idx < 727040){
    int e = idx - 722432;       // [9 taps][512 slots]
    int s = e & 511;
    int tap = e >> 9;
    int fn = s>>7, rr = s&127, fk2 = rr>>6, t = rr&63, q = t>>4, nr = t&15;
    int nn = fn*16+nr, k8 = fk2*4+q;
    const float* wp = c1w + nn*576 + k8*72 + tap;
    uint4 pk;
    pk.x = (u32)f2b(wp[0])  | ((u32)f2b(wp[9]) <<16);
    pk.y = (u32)f2b(wp[18]) | ((u32)f2b(wp[27])<<16);
    pk.z = (u32)f2b(wp[36]) | ((u32)f2b(wp[45])<<16);
    pk.w = (u32)f2b(wp[54]) | ((u32)f2b(wp[63])<<16);
    cwB[e] = pk;
  }
}

// ---------------------------------------------------------------------------
// Per-token LN stats (mean, rstd) of x [+ optional bf16 y2]. One wave/token.
// ---------------------------------------------------------------------------
__global__ __launch_bounds__(256) void stats_k(
    const float* __restrict__ x, const u16* __restrict__ yb,
    float* __restrict__ st)
{
  int wave = threadIdx.x>>6, lane = threadIdx.x&63;
  long t = (long)blockIdx.x*4 + wave;
  long idx = t*128 + lane*2;
  float2 vv = *reinterpret_cast<const float2*>(x+idx);
  if (yb){
    u32 p = *reinterpret_cast<const u32*>(yb+idx);
    vv.x += blo(p); vv.y += bhi(p);
  }
  float s = vv.x+vv.y, sq = vv.x*vv.x + vv.y*vv.y;
  #pragma unroll
  for (int o2=32;o2;o2>>=1){ s += __shfl_xor(s,o2); sq += __shfl_xor(sq,o2); }
  float mean = s*(1.f/128.f);
  float var = sq*(1.f/128.f) - mean*mean;
  if (lane==0){
    float2 ms; ms.x = mean; ms.y = rsqrtf(var + LN_EPS);
    *reinterpret_cast<float2*>(st + t*2) = ms;
  }
}

// ---------------------------------------------------------------------------
// QKV projection: block = 128 rows. A = LN1(x) staged ONCE (K=128, 32 KB),
// then 3 output chunks of 128 cols with B-frags loaded direct from L2-hot
// prepacked qkvB (no B LDS, no A re-read, no LN recompute).
// ---------------------------------------------------------------------------
__global__ __launch_bounds__(256,2) void qkv_k(
    const float* __restrict__ x, const float* __restrict__ st,
    const float* __restrict__ lng, const float* __restrict__ lnb,
    const u16* __restrict__ B16, const float* __restrict__ bias,
    u16* __restrict__ qkv)
{
  __shared__ uint4 As[2048];
  int tid = threadIdx.x, wave = tid>>6, lane = tid&63;
  int l15 = lane&15, quad = lane>>4;
  int bm = blockIdx.x*128;
  int wm = (wave>>1)*64, wn = (wave&1)*64;
  int wmf = wm>>4;
  #pragma unroll
  for (int pS=0; pS<8; pS++){
    int s = pS*256 + tid;
    int kh = s>>10, rem = s&1023;
    int fm = rem>>7, rr = rem&127, fk2 = rr>>6, t = rr&63, q2 = t>>4, mr = t&15;
    int m = fm*16+mr;
    int kk = kh*64 + (fk2*4+q2)*8;
    long row = bm + m;
    const float* xp = x + row*128 + kk;
    float4 a = *reinterpret_cast<const float4*>(xp);
    float4 b4 = *reinterpret_cast<const float4*>(xp+4);
    float v[8] = {a.x,a.y,a.z,a.w,b4.x,b4.y,b4.z,b4.w};
    float2 ms = *reinterpret_cast<const float2*>(st + row*2);
    #pragma unroll
    for (int j=0;j<8;j++) v[j] = (v[j]-ms.x)*ms.y*lng[kk+j] + lnb[kk+j];
    uint4 pk;
    pk.x = pk2(v[0],v[1]); pk.y = pk2(v[2],v[3]);
    pk.z = pk2(v[4],v[5]); pk.w = pk2(v[6],v[7]);
    As[s] = pk;
  }
  __syncthreads();
  #pragma unroll 1
  for (int nb=0; nb<3; nb++){
    floatx4 acc[4][4];
    #pragma unroll
    for (int i=0;i<4;i++)
      #pragma unroll
      for (int j=0;j<4;j++)
        #pragma unroll
        for (int e=0;e<4;e++) acc[i][j][e]=0.f;
    #pragma unroll
    for (int kh=0; kh<2; kh++)
      #pragma unroll
      for (int ks=0; ks<2; ks++){
        short8 af[4], bf[4];
        #pragma unroll
        for (int mt=0; mt<4; mt++)
          af[mt] = *reinterpret_cast<const short8*>(&As[kh*1024 + ((wmf+mt)*2+ks)*64 + lane]);
        #pragma unroll
        for (int nt=0; nt<4; nt++)
          bf[nt] = *reinterpret_cast<const short8*>(
              B16 + (nb*128 + wn + nt*16 + l15)*128 + kh*64 + (ks*4+quad)*8);
        #pragma unroll
        for (int mt=0;mt<4;mt++)
          #pragma unroll
          for (int nt=0;nt<4;nt++)
            acc[mt][nt] = __builtin_amdgcn_mfma_f32_16x16x32_bf16(af[mt], bf[nt], acc[mt][nt], 0,0,0);
      }
    #pragma unroll
    for (int nt=0;nt<4;nt++){
      int col = nb*128 + wn + nt*16 + l15;
      float bi = bias[col];
      #pragma unroll
      for (int mt=0;mt<4;mt++){
        int row0 = bm + wm + mt*16 + quad*4;
        #pragma unroll
        for (int r=0;r<4;r++)
          qkv[(long)(row0+r)*384 + col] = f2b(acc[mt][nt][r] + bi);
      }
    }
  }
}

// ---------------------------------------------------------------------------
// Fused FeedForward v6: x = y2b + W2 @ gelu(W1 @ LN2(x+y2b) + b1) + b2.
// r10 counters: MFMA 11.6 / VALU 40 / HBM 16 / Occ 20 -> latency-bound at
// 2 blocks/CU. Fix: drop the Hs double-buffer (r8 proved pipeline neutral)
// -> LDS 64->48 KB -> 3 blocks/CU (+50% co-residency), SAME 1024 blocks of
// 128 rows (weight traffic unchanged -- the r5 lesson). 64-col chunks,
// 2 barriers/chunk (r4-proven shape). Value sequence identical.
// ---------------------------------------------------------------------------
__global__ __launch_bounds__(256,3) void ff_k(
    const float* __restrict__ x, const u16* __restrict__ y2b,
    const float* __restrict__ st,
    const float* __restrict__ lng, const float* __restrict__ lnb,
    const u16* __restrict__ w1, const u16* __restrict__ w2,
    const float* __restrict__ b1, const float* __restrict__ b2,
    float* __restrict__ xo)
{
  __shared__ uint4 As[2048];     // 128 rows x 128 k (fragment-major), 32 KB
  __shared__ u16 Hs[8192];       // [128 rows][64 cols] swizzled, 16 KB
  int tid = threadIdx.x, wave = tid>>6, lane = tid&63;
  int l15 = lane&15, quad = lane>>4;
  int bm = blockIdx.x*128;
  int wm = (wave>>1)*64;        // row base (both gemms)
  int wn1 = (wave&1)*32;        // gemm1 col base within 64-col chunk
  int wn2 = (wave&1)*64;        // gemm2 output col base
  int wmf = wm>>4;
  // ---- stage A = LN2(x + y2b), K=128
  #pragma unroll
  for (int pS=0; pS<8; pS++){
    int s = pS*256 + tid;
    int kh = s>>10, rem = s&1023;
    int fm = rem>>7, rr = rem&127, fk2 = rr>>6, t = rr&63, q2 = t>>4, mr = t&15;
    int m = fm*16+mr;
    int kk = kh*64 + (fk2*4+q2)*8;
    long row = bm + m;
    const float* xp = x + row*128 + kk;
    float4 a = *reinterpret_cast<const float4*>(xp);
    float4 b4 = *reinterpret_cast<const float4*>(xp+4);
    float v[8] = {a.x,a.y,a.z,a.w,b4.x,b4.y,b4.z,b4.w};
    uint4 yv = *reinterpret_cast<const uint4*>(y2b + row*128 + kk);
    v[0]+=blo(yv.x); v[1]+=bhi(yv.x); v[2]+=blo(yv.y); v[3]+=bhi(yv.y);
    v[4]+=blo(yv.z); v[5]+=bhi(yv.z); v[6]+=blo(yv.w); v[7]+=bhi(yv.w);
    float2 ms = *reinterpret_cast<const float2*>(st + row*2);
    #pragma unroll
    for (int j=0;j<8;j++) v[j] = (v[j]-ms.x)*ms.y*lng[kk+j] + lnb[kk+j];
    uint4 pk;
    pk.x = pk2(v[0],v[1]); pk.y = pk2(v[2],v[3]);
    pk.z = pk2(v[4],v[5]); pk.w = pk2(v[6],v[7]);
    As[s] = pk;
  }
  __syncthreads();

  floatx4 acc2[4][4];
  #pragma unroll
  for (int i=0;i<4;i++)
    #pragma unroll
    for (int j=0;j<4;j++)
      #pragma unroll
      for (int e=0;e<4;e++) acc2[i][j][e]=0.f;

  #pragma unroll 1
  for (int hc=0; hc<8; hc++){
    // ---- gemm1: 64 rows x 32 cols per wave
    floatx4 acc1[4][2];
    #pragma unroll
    for (int i=0;i<4;i++)
      #pragma unroll
      for (int j=0;j<2;j++)
        #pragma unroll
        for (int e=0;e<4;e++) acc1[i][j][e]=0.f;
    #pragma unroll
    for (int kh=0; kh<2; kh++)
      #pragma unroll
      for (int ks=0; ks<2; ks++){
        short8 af[4], bf[2];
        #pragma unroll
        for (int mt=0; mt<4; mt++)
          af[mt] = *reinterpret_cast<const short8*>(&As[kh*1024 + ((wmf+mt)*2+ks)*64 + lane]);
        #pragma unroll
        for (int nt=0; nt<2; nt++)
          bf[nt] = *reinterpret_cast<const short8*>(
              w1 + (hc*64 + wn1 + nt*16 + l15)*128 + kh*64 + (ks*4+quad)*8);
        #pragma unroll
        for (int mt=0;mt<4;mt++)
          #pragma unroll
          for (int nt=0;nt<2;nt++)
            acc1[mt][nt] = __builtin_amdgcn_mfma_f32_16x16x32_bf16(af[mt], bf[nt], acc1[mt][nt], 0,0,0);
      }
    // ---- bias + gelu + pack to swizzled Hs
    {
      float b1v[2];
      #pragma unroll
      for (int nt=0;nt<2;nt++) b1v[nt] = b1[hc*64 + wn1 + nt*16 + l15];
      #pragma unroll
      for (int mt=0;mt<4;mt++)
        #pragma unroll
        for (int nt=0;nt<2;nt++){
          int col = wn1 + nt*16 + l15;
          int c8 = col>>3, c7 = col&7;
          #pragma unroll
          for (int r=0;r<4;r++){
            int row = wm + mt*16 + quad*4 + r;
            float val = acc1[mt][nt][r] + b1v[nt];
            Hs[(row<<6) + ((c8 ^ (row&7))<<3) + c7] = f2b(gelu_f(val));
          }
        }
    }
    __syncthreads();
    // ---- gemm2 partial over this 64-k chunk
    #pragma unroll
    for (int ks2=0; ks2<2; ks2++){
      short8 af[4], bf[4];
      #pragma unroll
      for (int mt=0;mt<4;mt++){
        int row = wm + mt*16 + l15;
        int col8 = ks2*4 + quad;
        af[mt] = *reinterpret_cast<const short8*>(
            &Hs[(row<<6) + ((col8 ^ (row&7))<<3)]);
      }
      #pragma unroll
      for (int nt=0;nt<4;nt++)
        bf[nt] = *reinterpret_cast<const short8*>(
            w2 + (wn2 + nt*16 + l15)*512 + hc*64 + ks2*32 + quad*8);
      #pragma unroll
      for (int mt=0;mt<4;mt++)
        #pragma unroll
        for (int nt=0;nt<4;nt++)
          acc2[mt][nt] = __builtin_amdgcn_mfma_f32_16x16x32_bf16(af[mt], bf[nt], acc2[mt][nt], 0,0,0);
    }
    if (hc < 7) __syncthreads();
  }
  // ---- epilogue: x = acc2 + b2 + y2b
  #pragma unroll
  for (int nt=0;nt<4;nt++){
    int col = wn2 + nt*16 + l15;
    float bi = b2[col];
    #pragma unroll
    for (int mt=0;mt<4;mt++){
      int row0 = bm + wm + mt*16 + quad*4;
      #pragma unroll
      for (int r=0;r<4;r++){
        long row = row0 + r;
        xo[row*128 + col] = acc2[mt][nt][r] + bi + blo((u32)y2b[row*128 + col]);
      }
    }
  }
}

// ---------------------------------------------------------------------------
// MFMA bf16 GEMM (encoder c2 + decoder only now).
// ---------------------------------------------------------------------------
constexpr int EPI_F32 = 0;
constexpr int EPI_DEC = 4;
constexpr int ASRC_B16 = 0;
constexpr int BSRC_F32 = 0;

template<int BN, int EPI, int ASRC, int BSRC>
__global__ __launch_bounds__(256) void gemm_k(
    const u16* __restrict__ A16, const float* __restrict__ Axf,
    const u16* __restrict__ Yadd, const float* __restrict__ st,
    const float* __restrict__ lng, const float* __restrict__ lnb,
    const float* __restrict__ Bsrc, const u16* __restrict__ B16,
    const float* __restrict__ bias, const u16* __restrict__ resid,
    float* __restrict__ outF, u16* __restrict__ outB,
    int M, int N, int K, int bNK,
    const float* __restrict__ qtp, const float* __restrict__ dctp)
{
  static_assert(BN==128 || BN==64, "BN");
  constexpr int MF = (BN==128)?4:2;
  constexpr int BSLOT = (BN/16)*128;
  __shared__ uint4 As[1024];
  __shared__ uint4 Bs[BSLOT];
  int tid = threadIdx.x;
  int wave = tid>>6, lane = tid&63;
  int bm = blockIdx.x * 128;
  int bn = blockIdx.y * BN;
  int wm = (BN==128)? (wave>>1)*64 : wave*32;
  int wn = (BN==128)? (wave&1)*64 : 0;
  int wmf = wm>>4, wnf = wn>>4;
  floatx4 acc[MF][4];
  #pragma unroll
  for (int i=0;i<MF;i++)
    #pragma unroll
    for (int j=0;j<4;j++)
      #pragma unroll
      for (int e=0;e<4;e++) acc[i][j][e]=0.f;

  for (int k0=0; k0<K; k0+=64){
    __syncthreads();
    #pragma unroll
    for (int pS=0; pS<4; pS++){
      int s = pS*256 + tid;
      int fm = s>>7, rr = s&127, fk2 = rr>>6, t = rr&63, quad = t>>4, mr = t&15;
      int m = fm*16+mr, k8 = fk2*4+quad;
      int kk = k0 + k8*8;
      long row = bm + m;
      As[s] = *reinterpret_cast<const uint4*>(A16 + row*K + kk);
    }
    #pragma unroll
    for (int pS=0; pS<BSLOT/256; pS++){
      int s = pS*256 + tid;
      int fn = s>>7, rr = s&127, fk2 = rr>>6, t = rr&63, quad = t>>4, nr = t&15;
      int nn = fn*16+nr, k8 = fk2*4+quad;
      int kk = k0 + k8*8;
      float v[8];
      if (bNK){
        const float* src = Bsrc + (long)(bn+nn)*K + kk;
        float4 a = *reinterpret_cast<const float4*>(src);
        float4 b = *reinterpret_cast<const float4*>(src+4);
        v[0]=a.x; v[1]=a.y; v[2]=a.z; v[3]=a.w; v[4]=b.x; v[5]=b.y; v[6]=b.z; v[7]=b.w;
      } else {
        #pragma unroll
        for (int j=0;j<8;j++) v[j] = Bsrc[(long)(kk+j)*N + bn + nn];
      }
      uint4 pk;
      pk.x = pk2(v[0],v[1]); pk.y = pk2(v[2],v[3]);
      pk.z = pk2(v[4],v[5]); pk.w = pk2(v[6],v[7]);
      Bs[s] = pk;
    }
    __syncthreads();
    #pragma unroll
    for (int ks=0; ks<2; ks++){
      short8 af[MF], bfr[4];
      #pragma unroll
      for (int mt=0; mt<MF; mt++)
        af[mt] = *reinterpret_cast<const short8*>(&As[((wmf+mt)*2+ks)*64 + lane]);
      #pragma unroll
      for (int nt=0; nt<4; nt++)
        bfr[nt] = *reinterpret_cast<const short8*>(&Bs[((wnf+nt)*2+ks)*64 + lane]);
      #pragma unroll
      for (int mt=0; mt<MF; mt++)
        #pragma unroll
        for (int nt=0; nt<4; nt++)
          acc[mt][nt] = __builtin_amdgcn_mfma_f32_16x16x32_bf16(af[mt], bfr[nt], acc[mt][nt], 0,0,0);
    }
  }
  #pragma unroll
  for (int mt=0; mt<MF; mt++){
    #pragma unroll
    for (int nt=0; nt<4; nt++){
      int col = bn + wn + nt*16 + (lane&15);
      int row0 = bm + wm + mt*16 + ((lane>>4)<<2);
      float bi = bias[col];
      #pragma unroll
      for (int rr2=0; rr2<4; rr2++){
        long row = row0 + rr2;
        float val = acc[mt][nt][rr2] + bi;
        if constexpr (EPI==EPI_F32){
          outF[row*N + col] = val;
        } else {
          int nn2 = (int)(row>>14), rm = (int)(row&16383);
          long didx = ((long)(nn2*64 + col)<<14) + rm;
          outF[didx] = dctp[didx] + val*qtp[nn2*64+col];
        }
      }
    }
  }
}

// ---------------------------------------------------------------------------
// MFMA local attention (v2, unchanged from r2 passing version).
// ---------------------------------------------------------------------------
__global__ __launch_bounds__(256) void attn_k(
    const u16* __restrict__ qkv, const float* __restrict__ rb,
    u16* __restrict__ y2b)
{
  __shared__ __align__(16) char lds_all[4*7168];
  int tid = threadIdx.x, wave = tid>>6, lane = tid&63;
  int l15 = lane & 15, quad = lane >> 4;
  char* wl = lds_all + wave*7168;
  u16* Kl = (u16*)wl;              // [32 px][40 u16]
  u16* Vt = (u16*)(wl + 2560);     // [32 ch][40 u16]
  float* ebl = (float*)(wl + 5120);// [23][21] masked exp(bias)
  int bi = blockIdx.x;
  int n = bi >> 8, t2 = bi & 255;
  int ty = (t2 >> 4) << 3, tx = (t2 & 15) << 3;
  int hh = wave;
  for (int k = lane; k < 512; k += 64){
    int dyp = k / 21, dxp = k - dyp*21;
    int dy = dyp - 7, dx = dxp - 7;
    float v = 0.f;
    if (((unsigned)dy < 7u) && ((unsigned)dx < 7u))
      v = __expf(rb[hh*49 + dy*7 + dx]);
    ebl[k] = v;
  }
  short8 qf[4];
  #pragma unroll
  for (int mt=0; mt<4; mt++){
    int m = mt*16 + l15;
    long tq = (long)n*16384 + (long)(ty + (m>>3))*128 + (tx + (m&7));
    qf[mt] = *reinterpret_cast<const short8*>(qkv + tq*384 + hh*32 + quad*8);
  }
  int pxs[2], c8s[2];
  #pragma unroll
  for (int ps=0; ps<2; ps++){
    int s = ps*64 + lane;
    pxs[ps] = s >> 2; c8s[ps] = s & 3;
  }
  auto load_chunk = [&](int c, uint4* krr, uint4* vrr){
    #pragma unroll
    for (int ps=0; ps<2; ps++){
      int hp = c*32 + pxs[ps];
      int hy = hp / 14, hx = hp % 14;
      int gy = ty + hy - 3, gx = tx + hx - 3;
      uint4 kz = {0,0,0,0}, vz = {0,0,0,0};
      if (((unsigned)gy < 128u) && ((unsigned)gx < 128u)){
        long t = (long)n*16384 + gy*128 + gx;
        const u16* p = qkv + t*384 + hh*32 + c8s[ps]*8;
        kz = *reinterpret_cast<const uint4*>(p + 128);
        vz = *reinterpret_cast<const uint4*>(p + 256);
      }
      krr[ps] = kz; vrr[ps] = vz;
    }
  };
  uint4 kr[2], vr[2];
  load_chunk(0, kr, vr);

  floatx4 oacc[4][2];
  float lsum[4];
  #pragma unroll
  for (int mt=0;mt<4;mt++){
    lsum[mt] = 0.f;
    #pragma unroll
    for (int nf=0;nf<2;nf++)
      #pragma unroll
      for (int e=0;e<4;e++) oacc[mt][nf][e]=0.f;
  }
  int qb0 = (l15>>3)*21 + (l15&7);
  bool lower = (lane < 32);
  bool sendRecv = (quad==0) || (quad==3);
  bool qodd = (quad & 1) != 0;
  bool q0q = (quad==0), q1q = (quad==1);

  for (int c=0; c<7; c++){
    #pragma unroll
    for (int ps=0; ps<2; ps++){
      *reinterpret_cast<uint4*>(Kl + pxs[ps]*40 + c8s[ps]*8) = kr[ps];
      u32 wv[4] = {vr[ps].x, vr[ps].y, vr[ps].z, vr[ps].w};
      #pragma unroll
      for (int i=0;i<8;i++){
        u16 val = (u16)((wv[i>>1] >> ((i&1)*16)) & 0xffffu);
        Vt[(c8s[ps]*8 + i)*40 + pxs[ps]] = val;
      }
    }
    uint4 kr2[2], vr2[2];
    if (c < 6) load_chunk(c+1, kr2, vr2);
    short8 kf0 = *reinterpret_cast<const short8*>(Kl + l15*40 + quad*8);
    short8 kf1 = *reinterpret_cast<const short8*>(Kl + (16 + l15)*40 + quad*8);
    short8 vf0 = *reinterpret_cast<const short8*>(Vt + l15*40 + quad*8);
    short8 vf1 = *reinterpret_cast<const short8*>(Vt + (16 + l15)*40 + quad*8);
    int hb[2][4];
    #pragma unroll
    for (int nf=0;nf<2;nf++)
      #pragma unroll
      for (int r=0;r<4;r++){
        int hp = c*32 + nf*16 + quad*4 + r;
        int hy = hp / 14, hx = hp - hy*14;
        hb[nf][r] = hy*21 + hx + 154;
      }
    #pragma unroll
    for (int mt=0;mt<4;mt++){
      floatx4 zz; zz[0]=0.f; zz[1]=0.f; zz[2]=0.f; zz[3]=0.f;
      floatx4 s0 = __builtin_amdgcn_mfma_f32_16x16x32_bf16(kf0, qf[mt], zz, 0,0,0);
      floatx4 s1 = __builtin_amdgcn_mfma_f32_16x16x32_bf16(kf1, qf[mt], zz, 0,0,0);
      int qb = qb0 + mt*42;
      float p0[4], p1[4];
      #pragma unroll
      for (int r=0;r<4;r++){
        p0[r] = __expf(s0[r]*ATTN_SCALE) * ebl[hb[0][r] - qb];
        p1[r] = __expf(s1[r]*ATTN_SCALE) * ebl[hb[1][r] - qb];
      }
      lsum[mt] += ((p0[0]+p0[1]) + (p0[2]+p0[3])) + ((p1[0]+p1[1]) + (p1[2]+p1[3]));
      u32 Aw = pk2(p0[0], p0[1]);
      u32 Bw = pk2(p0[2], p0[3]);
      u32 Cw = pk2(p1[0], p1[1]);
      u32 Dw = pk2(p1[2], p1[3]);
      u32 own0 = lower ? Aw : Cw;
      u32 own1 = lower ? Bw : Dw;
      u32 recv1 = (u32)__shfl_xor((int)(lower ? Cw : Aw), 32);
      u32 recv2 = (u32)__shfl_xor((int)(lower ? Dw : Bw), 32);
      u32 r3 = (u32)__shfl_xor((int)(sendRecv ? recv1 : own0), 16);
      u32 r4 = (u32)__shfl_xor((int)(sendRecv ? recv2 : own1), 16);
      uint4 paw;
      paw.x = qodd ? r3 : (q0q ? own0 : recv1);
      paw.y = qodd ? r4 : (q0q ? own1 : recv2);
      paw.z = qodd ? (q1q ? recv1 : own0) : r3;
      paw.w = qodd ? (q1q ? recv2 : own1) : r4;
      short8 pa = *reinterpret_cast<const short8*>(&paw);
      oacc[mt][0] = __builtin_amdgcn_mfma_f32_16x16x32_bf16(pa, vf0, oacc[mt][0], 0,0,0);
      oacc[mt][1] = __builtin_amdgcn_mfma_f32_16x16x32_bf16(pa, vf1, oacc[mt][1], 0,0,0);
    }
    #pragma unroll
    for (int ps=0; ps<2; ps++){ kr[ps]=kr2[ps]; vr[ps]=vr2[ps]; }
  }
  float rinv[4];
  #pragma unroll
  for (int mt=0;mt<4;mt++){
    float s = lsum[mt];
    s += __shfl_xor(s, 16);
    s += __shfl_xor(s, 32);
    rinv[mt] = 1.0f / s;
  }
  #pragma unroll
  for (int mt=0;mt<4;mt++){
    #pragma unroll
    for (int r=0;r<4;r++){
      int row = mt*16 + quad*4 + r;
      float sc = __shfl(rinv[mt], (quad<<2) | r);
      long t = (long)n*16384 + (long)(ty + (row>>3))*128 + (tx + (row&7));
      #pragma unroll
      for (int nfv=0;nfv<2;nfv++)
        y2b[t*128 + hh*32 + nfv*16 + l15] = f2b(oacc[mt][nfv][r] * sc);
    }
  }
}

__global__ __launch_bounds__(256) void cvt_k(const float* __restrict__ x, u16* __restrict__ o){
  long i = ((long)blockIdx.x*256 + threadIdx.x)*4;
  float4 vv = *reinterpret_cast<const float4*>(x+i);
  uint2 pk;
  pk.x = (u32)f2b(vv.x) | ((u32)f2b(vv.y)<<16);
  pk.y = (u32)f2b(vv.z) | ((u32)f2b(vv.w)<<16);
  *reinterpret_cast<uint2*>(o+i) = pk;
}

// ---------------------------------------------------------------------------
extern "C" void kernel_launch(void* const* d_in, const int* in_sizes, int n_in,
                              void* d_out, int out_size, void* d_ws, size_t ws_size,
                              hipStream_t stream)
{
  (void)in_sizes; (void)n_in; (void)out_size; (void)ws_size;
  const float* dct  = (const float*)d_in[0];
  const float* qt   = (const float*)d_in[1];
  const float* c1w  = (const float*)d_in[2];
  const float* c1b  = (const float*)d_in[3];
  const float* c2w  = (const float*)d_in[4];
  const float* c2b  = (const float*)d_in[5];
  const float* ln1g = (const float*)d_in[6];
  const float* ln1b = (const float*)d_in[7];
  const float* qw   = (const float*)d_in[8];
  const float* qbv  = (const float*)d_in[9];
  const float* kw   = (const float*)d_in[10];
  const float* kbv  = (const float*)d_in[11];
  const float* vw   = (const float*)d_in[12];
  const float* vbv  = (const float*)d_in[13];
  const float* rel  = (const float*)d_in[14];
  const float* ln2g = (const float*)d_in[15];
  const float* ln2b = (const float*)d_in[16];
  const float* ffw1 = (const float*)d_in[17];
  const float* ffb1 = (const float*)d_in[18];
  const float* ffw2 = (const float*)d_in[19];
  const float* ffb2 = (const float*)d_in[20];
  const float* decw = (const float*)d_in[21];
  const float* decb = (const float*)d_in[22];
  float* out = (float*)d_out;

  char* w = (char*)d_ws;
  float* x    = (float*)w;                          // 64 MB  [0, 64M)
  float* st   = (float*)(w + 67108864);             //  1 MB
  u16*  qkv   = (u16*)(w + 68157440);               // 96 MB  [T,384]
  u16*  y2b   = (u16*)(w + 168820736);               // 32 MB  [T,128]
  u16*  qkvB  = (u16*)(w + 202375168);              // 384 KB  packed qkv w
  u16*  ff1B  = (u16*)(w + 202768384);              // 512 KB
  u16*  ff2B  = (u16*)(w + 203292672);              // 512 KB
  float* biasB= (float*)(w + 203816960);            //   6 KB
  uint4* cwB  = (uint4*)(w + 203823104);            //  72 KB packed conv w
  u16*  tbuf = y2b;       // alias: encoder FiLM out (16 MB)
  u16*  dctT = qkv;       // alias: transposed dct (16 MB), dead before qkv gemm
  u16*  xb   = y2b;       // alias: decoder bf16 x

  prep_k<<<2840,256,0,stream>>>(qw,kw,vw,qbv,kbv,vbv,ffw1,ffw2,c1w,
                                qkvB,ff1B,ff2B,biasB,cwB);
  trans_k<<<512,256,0,stream>>>(dct, dctT);
  convgemm_k<<<1024,256,0,stream>>>(dctT, cwB, c1b, qt, tbuf);
  gemm_k<128,EPI_F32,ASRC_B16,BSRC_F32><<<dim3(1024,1),256,0,stream>>>(
      tbuf, nullptr,nullptr,nullptr,nullptr,nullptr,
      c2w, nullptr, c2b, nullptr, x, nullptr, T_TOK,128,64, 1, nullptr,nullptr);

  for (int l=0;l<4;l++){
    stats_k<<<32768,256,0,stream>>>(x, nullptr, st);
    qkv_k<<<1024,256,0,stream>>>(x, st, ln1g+l*128, ln1b+l*128,
        qkvB + (size_t)l*49152, biasB + l*384, qkv);
    attn_k<<<2048,256,0,stream>>>(qkv, rel+l*196, y2b);
    stats_k<<<32768,256,0,stream>>>(x, y2b, st);
    ff_k<<<1024,256,0,stream>>>(x, y2b, st, ln2g+l*128, ln2b+l*128,
        ff1B + (size_t)l*65536, ff2B + (size_t)l*65536,
        ffb1 + l*512, ffb2 + l*128, x);
  }
  cvt_k<<<16384,256,0,stream>>>(x, xb);
  gemm_k<64,EPI_DEC,ASRC_B16,BSRC_F32><<<dim3(1024,1),256,0,stream>>>(
      xb, nullptr,nullptr,nullptr,nullptr,nullptr,
      decw, nullptr, decb, nullptr, out, nullptr, T_TOK,64,128, 1, qt, dct);
}

// Round 12
// 1257.375 us; speedup vs baseline: 1.0966x; 1.0966x over previous
//
#include <hip/hip_runtime.h>
#include <hip/hip_bf16.h>

typedef __attribute__((ext_vector_type(8))) short short8;
typedef __attribute__((ext_vector_type(4))) float floatx4;
typedef unsigned short u16;
typedef unsigned int u32;

#define T_TOK 131072   // 8 * 128 * 128 tokens
#define LN_EPS 1e-5f
#define ATTN_SCALE 0.08838834764831845f   // 1/sqrt(128)

__device__ __forceinline__ u16 f2b(float f){
  __hip_bfloat16 h = __float2bfloat16(f);
  return *reinterpret_cast<u16*>(&h);
}
__device__ __forceinline__ float blo(u32 u){ union{u32 i; float f;} c; c.i = u<<16; return c.f; }
__device__ __forceinline__ float bhi(u32 u){ union{u32 i; float f;} c; c.i = u & 0xffff0000u; return c.f; }
__device__ __forceinline__ u32 pk2(float lo, float hi){
  return (u32)f2b(lo) | ((u32)f2b(hi)<<16);
}
// Branchless gelu: erf(v/sqrt2) via Abramowitz-Stegun 7.1.26 (max err 1.5e-7,
// far below the bf16 quantization applied right after). ~15 VALU ops.
__device__ __forceinline__ float gelu_f(float v){
  float xs = v * 0.70710678118654752f;
  float ax = fabsf(xs);
  float t = __builtin_amdgcn_rcpf(fmaf(0.3275911f, ax, 1.0f));
  float p = t*fmaf(t, fmaf(t, fmaf(t, fmaf(t, 1.061405429f, -1.453152027f),
                                   1.421413741f), -0.284496736f), 0.254829592f);
  float e = __expf(-ax*ax);
  float er = fmaf(-p, e, 1.0f);
  er = copysignf(er, v);
  return 0.5f*v*(1.0f + er);
}

// ---------------------------------------------------------------------------
// NCHW f32 -> [T,64] bf16 transpose
// ---------------------------------------------------------------------------
__global__ __launch_bounds__(256) void trans_k(
    const float* __restrict__ dct, u16* __restrict__ dctT)
{
  __shared__ u16 tl[256][66];
  int tid = threadIdx.x;
  int p = blockIdx.x*256 + tid;
  int n = p >> 14;
  int r = p & 16383;
  const float* dctn = dct + (long)n*64*16384;
  #pragma unroll
  for (int c=0;c<64;c++) tl[tid][c] = f2b(dctn[c*16384 + r]);
  __syncthreads();
  long base = (long)blockIdx.x*256*64;
  for (int pass=0; pass<64; pass++){
    int idx = pass*256 + tid;
    int pp = idx>>6, o = idx&63;
    dctT[base + idx] = tl[pp][o];
  }
}

// ---------------------------------------------------------------------------
// Encoder conv as MFMA GEMM, v2. Block = one image row (128 px) x 64 out ch.
// Halo rows staged once in XOR-swizzled LDS; weights prepacked fragment-order.
// ---------------------------------------------------------------------------
__global__ __launch_bounds__(256) void convgemm_k(
    const u16* __restrict__ dctT, const uint4* __restrict__ cwB,
    const float* __restrict__ c1b, const float* __restrict__ qt,
    u16* __restrict__ tbuf)
{
  __shared__ uint4 AL[3120];   // [3 rows][130 pxs][8 slots], slot = k8 ^ (pxs&7)
  int tid = threadIdx.x, wave = tid>>6, lane = tid&63;
  int l15 = lane & 15, quad = lane >> 4;
  int bm = blockIdx.x*128;
  int n = bm >> 14;
  int yb = (bm & 16383) >> 7;
  int wm = wave*32;
  for (int i = tid; i < 3120; i += 256){
    int row = i / 1040;
    int rem = i - row*1040;
    int pxs = rem >> 3;
    int k8 = rem & 7;
    int grow = yb + row - 1;
    int gpx = pxs - 1;
    uint4 v = {0,0,0,0};
    if (((unsigned)grow < 128u) && ((unsigned)gpx < 128u))
      v = *reinterpret_cast<const uint4*>(dctT + ((long)bm + (row-1)*128 + gpx)*64 + k8*8);
    AL[row*1040 + (pxs<<3) + (k8 ^ (pxs&7))] = v;
  }
  float qv[4], bi4[4];
  #pragma unroll
  for (int nt=0; nt<4; nt++){
    int col = nt*16 + l15;
    bi4[nt] = c1b[col];
    qv[nt] = qt[n*64 + col];
  }
  uint4 bcur[8];
  #pragma unroll
  for (int i=0;i<8;i++) bcur[i] = cwB[i*64 + lane];

  floatx4 acc[2][4];
  #pragma unroll
  for (int i=0;i<2;i++)
    #pragma unroll
    for (int j=0;j<4;j++)
      #pragma unroll
      for (int e=0;e<4;e++) acc[i][j][e]=0.f;

  __syncthreads();

  #pragma unroll
  for (int tap=0; tap<9; tap++){
    int dy = tap/3 - 1, dx = tap%3 - 1;
    uint4 bnx[8];
    if (tap < 8){
      #pragma unroll
      for (int i=0;i<8;i++) bnx[i] = cwB[(tap+1)*512 + i*64 + lane];
    }
    short8 af[2][2];
    #pragma unroll
    for (int mt=0; mt<2; mt++)
      #pragma unroll
      for (int ks=0; ks<2; ks++){
        int pxs = wm + mt*16 + l15 + dx + 1;
        int k8 = ks*4 + quad;
        af[mt][ks] = *reinterpret_cast<const short8*>(
            &AL[(dy+1)*1040 + (pxs<<3) + (k8 ^ (pxs&7))]);
      }
    #pragma unroll
    for (int ks=0; ks<2; ks++)
      #pragma unroll
      for (int mt=0; mt<2; mt++)
        #pragma unroll
        for (int nt=0; nt<4; nt++)
          acc[mt][nt] = __builtin_amdgcn_mfma_f32_16x16x32_bf16(
              af[mt][ks],
              *reinterpret_cast<const short8*>(&bcur[nt*2+ks]),
              acc[mt][nt], 0,0,0);
    #pragma unroll
    for (int i=0;i<8;i++) bcur[i] = bnx[i];
  }
  const u16* ALu = (const u16*)AL;
  #pragma unroll
  for (int mt=0; mt<2; mt++){
    #pragma unroll
    for (int nt=0; nt<4; nt++){
      int col = nt*16 + l15;
      int k8c = col>>3, sub = col&7;
      #pragma unroll
      for (int rr2=0; rr2<4; rr2++){
        int p = wm + mt*16 + quad*4 + rr2;
        int pxs = p + 1;
        float cen = blo((u32)ALu[(((130 + pxs)<<3) + (k8c ^ (pxs&7)))*8 + sub]);
        float val = acc[mt][nt][rr2] + bi4[nt];
        tbuf[((long)bm + p)*64 + col] = f2b(cen + qv[nt]*val);
      }
    }
  }
}

// ---------------------------------------------------------------------------
// Weight prepack: qkv/ff1/ff2 -> bf16 [n][k]; qkv bias concat (f32);
// conv weights -> bf16 fragment-order [tap][512 uint4-slots].
// ---------------------------------------------------------------------------
__global__ __launch_bounds__(256) void prep_k(
    const float* __restrict__ qw, const float* __restrict__ kw,
    const float* __restrict__ vw, const float* __restrict__ qb2,
    const float* __restrict__ kb2, const float* __restrict__ vb2,
    const float* __restrict__ f1, const float* __restrict__ f2,
    const float* __restrict__ c1w,
    u16* __restrict__ qkvB, u16* __restrict__ ff1B,
    u16* __restrict__ ff2B, float* __restrict__ biasB,
    uint4* __restrict__ cwB)
{
  int idx = blockIdx.x*256 + threadIdx.x;
  if (idx < 196608){
    int l = idx / 49152, r = idx % 49152;
    int sel = r / 16384, rr = r % 16384;
    int k = rr >> 7, nn = rr & 127;
    const float* src = (sel==0? qw : sel==1? kw : vw) + l*16384 + rr;
    qkvB[(size_t)l*49152 + (size_t)(sel*128 + nn)*128 + k] = f2b(*src);
  } else if (idx < 458752){
    int e = idx - 196608; int l = e >> 16, r = e & 65535;
    int k = r >> 9, nn = r & 511;
    ff1B[(size_t)l*65536 + (size_t)nn*128 + k] = f2b(f1[(size_t)l*65536 + r]);
  } else if (idx < 720896){
    int e = idx - 458752; int l = e >> 16, r = e & 65535;
    int k = r >> 7, nn = r & 127;
    ff2B[(size_t)l*65536 + (size_t)nn*512 + k] = f2b(f2[(size_t)l*65536 + r]);
  } else if (idx < 722432){
    int e = idx - 720896;       // [4][384]
    int l = e / 384, c = e % 384;
    int sel = c >> 7, nn = c & 127;
    const float* src = (sel==0? qb2 : sel==1? kb2 : vb2) + l*128 + nn;
    biasB[e] = *src;
  } else if (idx < 727040){
    int e = idx - 722432;       // [9 taps][512 slots]
    int s = e & 511;
    int tap = e >> 9;
    int fn = s>>7, rr = s&127, fk2 = rr>>6, t = rr&63, q = t>>4, nr = t&15;
    int nn = fn*16+nr, k8 = fk2*4+q;
    const float* wp = c1w + nn*576 + k8*72 + tap;
    uint4 pk;
    pk.x = (u32)f2b(wp[0])  | ((u32)f2b(wp[9]) <<16);
    pk.y = (u32)f2b(wp[18]) | ((u32)f2b(wp[27])<<16);
    pk.z = (u32)f2b(wp[36]) | ((u32)f2b(wp[45])<<16);
    pk.w = (u32)f2b(wp[54]) | ((u32)f2b(wp[63])<<16);
    cwB[e] = pk;
  }
}

// ---------------------------------------------------------------------------
// Per-token LN stats (mean, rstd) of x [+ optional bf16 y2]. One wave/token.
// ---------------------------------------------------------------------------
__global__ __launch_bounds__(256) void stats_k(
    const float* __restrict__ x, const u16* __restrict__ yb,
    float* __restrict__ st)
{
  int wave = threadIdx.x>>6, lane = threadIdx.x&63;
  long t = (long)blockIdx.x*4 + wave;
  long idx = t*128 + lane*2;
  float2 vv = *reinterpret_cast<const float2*>(x+idx);
  if (yb){
    u32 p = *reinterpret_cast<const u32*>(yb+idx);
    vv.x += blo(p); vv.y += bhi(p);
  }
  float s = vv.x+vv.y, sq = vv.x*vv.x + vv.y*vv.y;
  #pragma unroll
  for (int o2=32;o2;o2>>=1){ s += __shfl_xor(s,o2); sq += __shfl_xor(sq,o2); }
  float mean = s*(1.f/128.f);
  float var = sq*(1.f/128.f) - mean*mean;
  if (lane==0){
    float2 ms; ms.x = mean; ms.y = rsqrtf(var + LN_EPS);
    *reinterpret_cast<float2*>(st + t*2) = ms;
  }
}

// ---------------------------------------------------------------------------
// QKV projection: block = 128 rows. A = LN1(x) staged ONCE (K=128, 32 KB),
// then 3 output chunks of 128 cols with B-frags loaded direct from L2-hot
// prepacked qkvB (no B LDS, no A re-read, no LN recompute).
// ---------------------------------------------------------------------------
__global__ __launch_bounds__(256,2) void qkv_k(
    const float* __restrict__ x, const float* __restrict__ st,
    const float* __restrict__ lng, const float* __restrict__ lnb,
    const u16* __restrict__ B16, const float* __restrict__ bias,
    u16* __restrict__ qkv)
{
  __shared__ uint4 As[2048];
  int tid = threadIdx.x, wave = tid>>6, lane = tid&63;
  int l15 = lane&15, quad = lane>>4;
  int bm = blockIdx.x*128;
  int wm = (wave>>1)*64, wn = (wave&1)*64;
  int wmf = wm>>4;
  #pragma unroll
  for (int pS=0; pS<8; pS++){
    int s = pS*256 + tid;
    int kh = s>>10, rem = s&1023;
    int fm = rem>>7, rr = rem&127, fk2 = rr>>6, t = rr&63, q2 = t>>4, mr = t&15;
    int m = fm*16+mr;
    int kk = kh*64 + (fk2*4+q2)*8;
    long row = bm + m;
    const float* xp = x + row*128 + kk;
    float4 a = *reinterpret_cast<const float4*>(xp);
    float4 b4 = *reinterpret_cast<const float4*>(xp+4);
    float v[8] = {a.x,a.y,a.z,a.w,b4.x,b4.y,b4.z,b4.w};
    float2 ms = *reinterpret_cast<const float2*>(st + row*2);
    #pragma unroll
    for (int j=0;j<8;j++) v[j] = (v[j]-ms.x)*ms.y*lng[kk+j] + lnb[kk+j];
    uint4 pk;
    pk.x = pk2(v[0],v[1]); pk.y = pk2(v[2],v[3]);
    pk.z = pk2(v[4],v[5]); pk.w = pk2(v[6],v[7]);
    As[s] = pk;
  }
  __syncthreads();
  #pragma unroll 1
  for (int nb=0; nb<3; nb++){
    floatx4 acc[4][4];
    #pragma unroll
    for (int i=0;i<4;i++)
      #pragma unroll
      for (int j=0;j<4;j++)
        #pragma unroll
        for (int e=0;e<4;e++) acc[i][j][e]=0.f;
    #pragma unroll
    for (int kh=0; kh<2; kh++)
      #pragma unroll
      for (int ks=0; ks<2; ks++){
        short8 af[4], bf[4];
        #pragma unroll
        for (int mt=0; mt<4; mt++)
          af[mt] = *reinterpret_cast<const short8*>(&As[kh*1024 + ((wmf+mt)*2+ks)*64 + lane]);
        #pragma unroll
        for (int nt=0; nt<4; nt++)
          bf[nt] = *reinterpret_cast<const short8*>(
              B16 + (nb*128 + wn + nt*16 + l15)*128 + kh*64 + (ks*4+quad)*8);
        #pragma unroll
        for (int mt=0;mt<4;mt++)
          #pragma unroll
          for (int nt=0;nt<4;nt++)
            acc[mt][nt] = __builtin_amdgcn_mfma_f32_16x16x32_bf16(af[mt], bf[nt], acc[mt][nt], 0,0,0);
      }
    #pragma unroll
    for (int nt=0;nt<4;nt++){
      int col = nb*128 + wn + nt*16 + l15;
      float bi = bias[col];
      #pragma unroll
      for (int mt=0;mt<4;mt++){
        int row0 = bm + wm + mt*16 + quad*4;
        #pragma unroll
        for (int r=0;r<4;r++)
          qkv[(long)(row0+r)*384 + col] = f2b(acc[mt][nt][r] + bi);
      }
    }
  }
}

// ---------------------------------------------------------------------------
// Fused FeedForward v5b (r10-verified, 118.5 us): x = y2b + W2 @
// gelu(W1 @ LN2(x+y2b) + b1) + b2. r8 pipelined structure + fast gelu.
// r11 lesson: do NOT cap VGPR below ~112 (launch_bounds(256,3) -> 84 VGPR
// -> scratch spills -> +20 MB traffic, 182 us). VGPR is the binding
// occupancy constraint here; 64 KB LDS / 2 blocks/CU is the optimum found.
// ---------------------------------------------------------------------------
__global__ __launch_bounds__(256,2) void ff_k(
    const float* __restrict__ x, const u16* __restrict__ y2b,
    const float* __restrict__ st,
    const float* __restrict__ lng, const float* __restrict__ lnb,
    const u16* __restrict__ w1, const u16* __restrict__ w2,
    const float* __restrict__ b1, const float* __restrict__ b2,
    float* __restrict__ xo)
{
  __shared__ uint4 As[2048];     // 128 rows x 128 k (fragment-major)
  __shared__ u16 Hs[2][8192];    // [128 rows][64 cols] swizzled, dbuf
  int tid = threadIdx.x, wave = tid>>6, lane = tid&63;
  int l15 = lane&15, quad = lane>>4;
  int bm = blockIdx.x*128;
  int wm = (wave>>1)*64;        // row base (both gemms)
  int wn1 = (wave&1)*32;        // gemm1 col base within 64-col chunk
  int wn2 = (wave&1)*64;        // gemm2 output col base
  int wmf = wm>>4;
  // ---- stage A = LN2(x + y2b), K=128
  #pragma unroll
  for (int pS=0; pS<8; pS++){
    int s = pS*256 + tid;
    int kh = s>>10, rem = s&1023;
    int fm = rem>>7, rr = rem&127, fk2 = rr>>6, t = rr&63, q2 = t>>4, mr = t&15;
    int m = fm*16+mr;
    int kk = kh*64 + (fk2*4+q2)*8;
    long row = bm + m;
    const float* xp = x + row*128 + kk;
    float4 a = *reinterpret_cast<const float4*>(xp);
    float4 b4 = *reinterpret_cast<const float4*>(xp+4);
    float v[8] = {a.x,a.y,a.z,a.w,b4.x,b4.y,b4.z,b4.w};
    uint4 yv = *reinterpret_cast<const uint4*>(y2b + row*128 + kk);
    v[0]+=blo(yv.x); v[1]+=bhi(yv.x); v[2]+=blo(yv.y); v[3]+=bhi(yv.y);
    v[4]+=blo(yv.z); v[5]+=bhi(yv.z); v[6]+=blo(yv.w); v[7]+=bhi(yv.w);
    float2 ms = *reinterpret_cast<const float2*>(st + row*2);
    #pragma unroll
    for (int j=0;j<8;j++) v[j] = (v[j]-ms.x)*ms.y*lng[kk+j] + lnb[kk+j];
    uint4 pk;
    pk.x = pk2(v[0],v[1]); pk.y = pk2(v[2],v[3]);
    pk.z = pk2(v[4],v[5]); pk.w = pk2(v[6],v[7]);
    As[s] = pk;
  }
  __syncthreads();

  floatx4 acc2[4][4];
  #pragma unroll
  for (int i=0;i<4;i++)
    #pragma unroll
    for (int j=0;j<4;j++)
      #pragma unroll
      for (int e=0;e<4;e++) acc2[i][j][e]=0.f;

  // gemm1 of one 64-col chunk -> acc1[4][2] (64 rows x 32 cols per wave)
  auto GEMM1 = [&](int hc, floatx4 (&acc1)[4][2]){
    #pragma unroll
    for (int i=0;i<4;i++)
      #pragma unroll
      for (int j=0;j<2;j++)
        #pragma unroll
        for (int e=0;e<4;e++) acc1[i][j][e]=0.f;
    #pragma unroll
    for (int kh=0; kh<2; kh++)
      #pragma unroll
      for (int ks=0; ks<2; ks++){
        short8 af[4], bf[2];
        #pragma unroll
        for (int mt=0; mt<4; mt++)
          af[mt] = *reinterpret_cast<const short8*>(&As[kh*1024 + ((wmf+mt)*2+ks)*64 + lane]);
        #pragma unroll
        for (int nt=0; nt<2; nt++)
          bf[nt] = *reinterpret_cast<const short8*>(
              w1 + (hc*64 + wn1 + nt*16 + l15)*128 + kh*64 + (ks*4+quad)*8);
        #pragma unroll
        for (int mt=0;mt<4;mt++)
          #pragma unroll
          for (int nt=0;nt<2;nt++)
            acc1[mt][nt] = __builtin_amdgcn_mfma_f32_16x16x32_bf16(af[mt], bf[nt], acc1[mt][nt], 0,0,0);
      }
  };
  // bias+gelu+pack acc1 into Hs[hc&1] (swizzled [128][64])
  auto GELUW = [&](int hc, floatx4 (&acc1)[4][2]){
    float b1v[2];
    #pragma unroll
    for (int nt=0;nt<2;nt++) b1v[nt] = b1[hc*64 + wn1 + nt*16 + l15];
    u16* hb = Hs[hc&1];
    #pragma unroll
    for (int mt=0;mt<4;mt++)
      #pragma unroll
      for (int nt=0;nt<2;nt++){
        int col = wn1 + nt*16 + l15;
        int c8 = col>>3, c7 = col&7;
        #pragma unroll
        for (int r=0;r<4;r++){
          int row = wm + mt*16 + quad*4 + r;
          float val = acc1[mt][nt][r] + b1v[nt];
          hb[(row<<6) + ((c8 ^ (row&7))<<3) + c7] = f2b(gelu_f(val));
        }
      }
  };
  // gemm2 partial over one 64-k chunk
  auto GEMM2 = [&](int hc){
    const u16* hb = Hs[hc&1];
    #pragma unroll
    for (int ks2=0; ks2<2; ks2++){
      short8 af[4], bf[4];
      #pragma unroll
      for (int mt=0;mt<4;mt++){
        int row = wm + mt*16 + l15;
        int col8 = ks2*4 + quad;
        af[mt] = *reinterpret_cast<const short8*>(
            &hb[(row<<6) + ((col8 ^ (row&7))<<3)]);
      }
      #pragma unroll
      for (int nt=0;nt<4;nt++)
        bf[nt] = *reinterpret_cast<const short8*>(
            w2 + (wn2 + nt*16 + l15)*512 + hc*64 + ks2*32 + quad*8);
      #pragma unroll
      for (int mt=0;mt<4;mt++)
        #pragma unroll
        for (int nt=0;nt<4;nt++)
          acc2[mt][nt] = __builtin_amdgcn_mfma_f32_16x16x32_bf16(af[mt], bf[nt], acc2[mt][nt], 0,0,0);
    }
  };

  // ---- pipelined main loop
  {
    floatx4 acc1a[4][2];
    GEMM1(0, acc1a);
    GELUW(0, acc1a);
  }
  __syncthreads();
  #pragma unroll 1
  for (int hc=0; hc<8; hc++){
    floatx4 acc1n[4][2];
    if (hc < 7) GEMM1(hc+1, acc1n);   // independent of GEMM2(hc) below
    GEMM2(hc);
    if (hc < 7){
      GELUW(hc+1, acc1n);
      __syncthreads();
    }
  }
  // ---- epilogue: x = acc2 + b2 + y2b
  #pragma unroll
  for (int nt=0;nt<4;nt++){
    int col = wn2 + nt*16 + l15;
    float bi = b2[col];
    #pragma unroll
    for (int mt=0;mt<4;mt++){
      int row0 = bm + wm + mt*16 + quad*4;
      #pragma unroll
      for (int r=0;r<4;r++){
        long row = row0 + r;
        xo[row*128 + col] = acc2[mt][nt][r] + bi + blo((u32)y2b[row*128 + col]);
      }
    }
  }
}

// ---------------------------------------------------------------------------
// MFMA bf16 GEMM (encoder c2 + decoder only now).
// ---------------------------------------------------------------------------
constexpr int EPI_F32 = 0;
constexpr int EPI_DEC = 4;
constexpr int ASRC_B16 = 0;
constexpr int BSRC_F32 = 0;

template<int BN, int EPI, int ASRC, int BSRC>
__global__ __launch_bounds__(256) void gemm_k(
    const u16* __restrict__ A16, const float* __restrict__ Axf,
    const u16* __restrict__ Yadd, const float* __restrict__ st,
    const float* __restrict__ lng, const float* __restrict__ lnb,
    const float* __restrict__ Bsrc, const u16* __restrict__ B16,
    const float* __restrict__ bias, const u16* __restrict__ resid,
    float* __restrict__ outF, u16* __restrict__ outB,
    int M, int N, int K, int bNK,
    const float* __restrict__ qtp, const float* __restrict__ dctp)
{
  static_assert(BN==128 || BN==64, "BN");
  constexpr int MF = (BN==128)?4:2;
  constexpr int BSLOT = (BN/16)*128;
  __shared__ uint4 As[1024];
  __shared__ uint4 Bs[BSLOT];
  int tid = threadIdx.x;
  int wave = tid>>6, lane = tid&63;
  int bm = blockIdx.x * 128;
  int bn = blockIdx.y * BN;
  int wm = (BN==128)? (wave>>1)*64 : wave*32;
  int wn = (BN==128)? (wave&1)*64 : 0;
  int wmf = wm>>4, wnf = wn>>4;
  floatx4 acc[MF][4];
  #pragma unroll
  for (int i=0;i<MF;i++)
    #pragma unroll
    for (int j=0;j<4;j++)
      #pragma unroll
      for (int e=0;e<4;e++) acc[i][j][e]=0.f;

  for (int k0=0; k0<K; k0+=64){
    __syncthreads();
    #pragma unroll
    for (int pS=0; pS<4; pS++){
      int s = pS*256 + tid;
      int fm = s>>7, rr = s&127, fk2 = rr>>6, t = rr&63, quad = t>>4, mr = t&15;
      int m = fm*16+mr, k8 = fk2*4+quad;
      int kk = k0 + k8*8;
      long row = bm + m;
      As[s] = *reinterpret_cast<const uint4*>(A16 + row*K + kk);
    }
    #pragma unroll
    for (int pS=0; pS<BSLOT/256; pS++){
      int s = pS*256 + tid;
      int fn = s>>7, rr = s&127, fk2 = rr>>6, t = rr&63, quad = t>>4, nr = t&15;
      int nn = fn*16+nr, k8 = fk2*4+quad;
      int kk = k0 + k8*8;
      float v[8];
      if (bNK){
        const float* src = Bsrc + (long)(bn+nn)*K + kk;
        float4 a = *reinterpret_cast<const float4*>(src);
        float4 b = *reinterpret_cast<const float4*>(src+4);
        v[0]=a.x; v[1]=a.y; v[2]=a.z; v[3]=a.w; v[4]=b.x; v[5]=b.y; v[6]=b.z; v[7]=b.w;
      } else {
        #pragma unroll
        for (int j=0;j<8;j++) v[j] = Bsrc[(long)(kk+j)*N + bn + nn];
      }
      uint4 pk;
      pk.x = pk2(v[0],v[1]); pk.y = pk2(v[2],v[3]);
      pk.z = pk2(v[4],v[5]); pk.w = pk2(v[6],v[7]);
      Bs[s] = pk;
    }
    __syncthreads();
    #pragma unroll
    for (int ks=0; ks<2; ks++){
      short8 af[MF], bfr[4];
      #pragma unroll
      for (int mt=0; mt<MF; mt++)
        af[mt] = *reinterpret_cast<const short8*>(&As[((wmf+mt)*2+ks)*64 + lane]);
      #pragma unroll
      for (int nt=0; nt<4; nt++)
        bfr[nt] = *reinterpret_cast<const short8*>(&Bs[((wnf+nt)*2+ks)*64 + lane]);
      #pragma unroll
      for (int mt=0; mt<MF; mt++)
        #pragma unroll
        for (int nt=0; nt<4; nt++)
          acc[mt][nt] = __builtin_amdgcn_mfma_f32_16x16x32_bf16(af[mt], bfr[nt], acc[mt][nt], 0,0,0);
    }
  }
  #pragma unroll
  for (int mt=0; mt<MF; mt++){
    #pragma unroll
    for (int nt=0; nt<4; nt++){
      int col = bn + wn + nt*16 + (lane&15);
      int row0 = bm + wm + mt*16 + ((lane>>4)<<2);
      float bi = bias[col];
      #pragma unroll
      for (int rr2=0; rr2<4; rr2++){
        long row = row0 + rr2;
        float val = acc[mt][nt][rr2] + bi;
        if constexpr (EPI==EPI_F32){
          outF[row*N + col] = val;
        } else {
          int nn2 = (int)(row>>14), rm = (int)(row&16383);
          long didx = ((long)(nn2*64 + col)<<14) + rm;
          outF[didx] = dctp[didx] + val*qtp[nn2*64+col];
        }
      }
    }
  }
}

// ---------------------------------------------------------------------------
// MFMA local attention (v2, unchanged from r2 passing version).
// ---------------------------------------------------------------------------
__global__ __launch_bounds__(256) void attn_k(
    const u16* __restrict__ qkv, const float* __restrict__ rb,
    u16* __restrict__ y2b)
{
  __shared__ __align__(16) char lds_all[4*7168];
  int tid = threadIdx.x, wave = tid>>6, lane = tid&63;
  int l15 = lane & 15, quad = lane >> 4;
  char* wl = lds_all + wave*7168;
  u16* Kl = (u16*)wl;              // [32 px][40 u16]
  u16* Vt = (u16*)(wl + 2560);     // [32 ch][40 u16]
  float* ebl = (float*)(wl + 5120);// [23][21] masked exp(bias)
  int bi = blockIdx.x;
  int n = bi >> 8, t2 = bi & 255;
  int ty = (t2 >> 4) << 3, tx = (t2 & 15) << 3;
  int hh = wave;
  for (int k = lane; k < 512; k += 64){
    int dyp = k / 21, dxp = k - dyp*21;
    int dy = dyp - 7, dx = dxp - 7;
    float v = 0.f;
    if (((unsigned)dy < 7u) && ((unsigned)dx < 7u))
      v = __expf(rb[hh*49 + dy*7 + dx]);
    ebl[k] = v;
  }
  short8 qf[4];
  #pragma unroll
  for (int mt=0; mt<4; mt++){
    int m = mt*16 + l15;
    long tq = (long)n*16384 + (long)(ty + (m>>3))*128 + (tx + (m&7));
    qf[mt] = *reinterpret_cast<const short8*>(qkv + tq*384 + hh*32 + quad*8);
  }
  int pxs[2], c8s[2];
  #pragma unroll
  for (int ps=0; ps<2; ps++){
    int s = ps*64 + lane;
    pxs[ps] = s >> 2; c8s[ps] = s & 3;
  }
  auto load_chunk = [&](int c, uint4* krr, uint4* vrr){
    #pragma unroll
    for (int ps=0; ps<2; ps++){
      int hp = c*32 + pxs[ps];
      int hy = hp / 14, hx = hp % 14;
      int gy = ty + hy - 3, gx = tx + hx - 3;
      uint4 kz = {0,0,0,0}, vz = {0,0,0,0};
      if (((unsigned)gy < 128u) && ((unsigned)gx < 128u)){
        long t = (long)n*16384 + gy*128 + gx;
        const u16* p = qkv + t*384 + hh*32 + c8s[ps]*8;
        kz = *reinterpret_cast<const uint4*>(p + 128);
        vz = *reinterpret_cast<const uint4*>(p + 256);
      }
      krr[ps] = kz; vrr[ps] = vz;
    }
  };
  uint4 kr[2], vr[2];
  load_chunk(0, kr, vr);

  floatx4 oacc[4][2];
  float lsum[4];
  #pragma unroll
  for (int mt=0;mt<4;mt++){
    lsum[mt] = 0.f;
    #pragma unroll
    for (int nf=0;nf<2;nf++)
      #pragma unroll
      for (int e=0;e<4;e++) oacc[mt][nf][e]=0.f;
  }
  int qb0 = (l15>>3)*21 + (l15&7);
  bool lower = (lane < 32);
  bool sendRecv = (quad==0) || (quad==3);
  bool qodd = (quad & 1) != 0;
  bool q0q = (quad==0), q1q = (quad==1);

  for (int c=0; c<7; c++){
    #pragma unroll
    for (int ps=0; ps<2; ps++){
      *reinterpret_cast<uint4*>(Kl + pxs[ps]*40 + c8s[ps]*8) = kr[ps];
      u32 wv[4] = {vr[ps].x, vr[ps].y, vr[ps].z, vr[ps].w};
      #pragma unroll
      for (int i=0;i<8;i++){
        u16 val = (u16)((wv[i>>1] >> ((i&1)*16)) & 0xffffu);
        Vt[(c8s[ps]*8 + i)*40 + pxs[ps]] = val;
      }
    }
    uint4 kr2[2], vr2[2];
    if (c < 6) load_chunk(c+1, kr2, vr2);
    short8 kf0 = *reinterpret_cast<const short8*>(Kl + l15*40 + quad*8);
    short8 kf1 = *reinterpret_cast<const short8*>(Kl + (16 + l15)*40 + quad*8);
    short8 vf0 = *reinterpret_cast<const short8*>(Vt + l15*40 + quad*8);
    short8 vf1 = *reinterpret_cast<const short8*>(Vt + (16 + l15)*40 + quad*8);
    int hb[2][4];
    #pragma unroll
    for (int nf=0;nf<2;nf++)
      #pragma unroll
      for (int r=0;r<4;r++){
        int hp = c*32 + nf*16 + quad*4 + r;
        int hy = hp / 14, hx = hp - hy*14;
        hb[nf][r] = hy*21 + hx + 154;
      }
    #pragma unroll
    for (int mt=0;mt<4;mt++){
      floatx4 zz; zz[0]=0.f; zz[1]=0.f; zz[2]=0.f; zz[3]=0.f;
      floatx4 s0 = __builtin_amdgcn_mfma_f32_16x16x32_bf16(kf0, qf[mt], zz, 0,0,0);
      floatx4 s1 = __builtin_amdgcn_mfma_f32_16x16x32_bf16(kf1, qf[mt], zz, 0,0,0);
      int qb = qb0 + mt*42;
      float p0[4], p1[4];
      #pragma unroll
      for (int r=0;r<4;r++){
        p0[r] = __expf(s0[r]*ATTN_SCALE) * ebl[hb[0][r] - qb];
        p1[r] = __expf(s1[r]*ATTN_SCALE) * ebl[hb[1][r] - qb];
      }
      lsum[mt] += ((p0[0]+p0[1]) + (p0[2]+p0[3])) + ((p1[0]+p1[1]) + (p1[2]+p1[3]));
      u32 Aw = pk2(p0[0], p0[1]);
      u32 Bw = pk2(p0[2], p0[3]);
      u32 Cw = pk2(p1[0], p1[1]);
      u32 Dw = pk2(p1[2], p1[3]);
      u32 own0 = lower ? Aw : Cw;
      u32 own1 = lower ? Bw : Dw;
      u32 recv1 = (u32)__shfl_xor((int)(lower ? Cw : Aw), 32);
      u32 recv2 = (u32)__shfl_xor((int)(lower ? Dw : Bw), 32);
      u32 r3 = (u32)__shfl_xor((int)(sendRecv ? recv1 : own0), 16);
      u32 r4 = (u32)__shfl_xor((int)(sendRecv ? recv2 : own1), 16);
      uint4 paw;
      paw.x = qodd ? r3 : (q0q ? own0 : recv1);
      paw.y = qodd ? r4 : (q0q ? own1 : recv2);
      paw.z = qodd ? (q1q ? recv1 : own0) : r3;
      paw.w = qodd ? (q1q ? recv2 : own1) : r4;
      short8 pa = *reinterpret_cast<const short8*>(&paw);
      oacc[mt][0] = __builtin_amdgcn_mfma_f32_16x16x32_bf16(pa, vf0, oacc[mt][0], 0,0,0);
      oacc[mt][1] = __builtin_amdgcn_mfma_f32_16x16x32_bf16(pa, vf1, oacc[mt][1], 0,0,0);
    }
    #pragma unroll
    for (int ps=0; ps<2; ps++){ kr[ps]=kr2[ps]; vr[ps]=vr2[ps]; }
  }
  float rinv[4];
  #pragma unroll
  for (int mt=0;mt<4;mt++){
    float s = lsum[mt];
    s += __shfl_xor(s, 16);
    s += __shfl_xor(s, 32);
    rinv[mt] = 1.0f / s;
  }
  #pragma unroll
  for (int mt=0;mt<4;mt++){
    #pragma unroll
    for (int r=0;r<4;r++){
      int row = mt*16 + quad*4 + r;
      float sc = __shfl(rinv[mt], (quad<<2) | r);
      long t = (long)n*16384 + (long)(ty + (row>>3))*128 + (tx + (row&7));
      #pragma unroll
      for (int nfv=0;nfv<2;nfv++)
        y2b[t*128 + hh*32 + nfv*16 + l15] = f2b(oacc[mt][nfv][r] * sc);
    }
  }
}

__global__ __launch_bounds__(256) void cvt_k(const float* __restrict__ x, u16* __restrict__ o){
  long i = ((long)blockIdx.x*256 + threadIdx.x)*4;
  float4 vv = *reinterpret_cast<const float4*>(x+i);
  uint2 pk;
  pk.x = (u32)f2b(vv.x) | ((u32)f2b(vv.y)<<16);
  pk.y = (u32)f2b(vv.z) | ((u32)f2b(vv.w)<<16);
  *reinterpret_cast<uint2*>(o+i) = pk;
}

// ---------------------------------------------------------------------------
extern "C" void kernel_launch(void* const* d_in, const int* in_sizes, int n_in,
                              void* d_out, int out_size, void* d_ws, size_t ws_size,
                              hipStream_t stream)
{
  (void)in_sizes; (void)n_in; (void)out_size; (void)ws_size;
  const float* dct  = (const float*)d_in[0];
  const float* qt   = (const float*)d_in[1];
  const float* c1w  = (const float*)d_in[2];
  const float* c1b  = (const float*)d_in[3];
  const float* c2w  = (const float*)d_in[4];
  const float* c2b  = (const float*)d_in[5];
  const float* ln1g = (const float*)d_in[6];
  const float* ln1b = (const float*)d_in[7];
  const float* qw   = (const float*)d_in[8];
  const float* qbv  = (const float*)d_in[9];
  const float* kw   = (const float*)d_in[10];
  const float* kbv  = (const float*)d_in[11];
  const float* vw   = (const float*)d_in[12];
  const float* vbv  = (const float*)d_in[13];
  const float* rel  = (const float*)d_in[14];
  const float* ln2g = (const float*)d_in[15];
  const float* ln2b = (const float*)d_in[16];
  const float* ffw1 = (const float*)d_in[17];
  const float* ffb1 = (const float*)d_in[18];
  const float* ffw2 = (const float*)d_in[19];
  const float* ffb2 = (const float*)d_in[20];
  const float* decw = (const float*)d_in[21];
  const float* decb = (const float*)d_in[22];
  float* out = (float*)d_out;

  char* w = (char*)d_ws;
  float* x    = (float*)w;                          // 64 MB  [0, 64M)
  float* st   = (float*)(w + 67108864);             //  1 MB
  u16*  qkv   = (u16*)(w + 68157440);               // 96 MB  [T,384]
  u16*  y2b   = (u16*)(w + 168820736);              // 32 MB  [T,128]
  u16*  qkvB  = (u16*)(w + 202375168);              // 384 KB  packed qkv w
  u16*  ff1B  = (u16*)(w + 202768384);              // 512 KB
  u16*  ff2B  = (u16*)(w + 203292672);              // 512 KB
  float* biasB= (float*)(w + 203816960);            //   6 KB
  uint4* cwB  = (uint4*)(w + 203823104);            //  72 KB packed conv w
  u16*  tbuf = y2b;       // alias: encoder FiLM out (16 MB)
  u16*  dctT = qkv;       // alias: transposed dct (16 MB), dead before qkv gemm
  u16*  xb   = y2b;       // alias: decoder bf16 x

  prep_k<<<2840,256,0,stream>>>(qw,kw,vw,qbv,kbv,vbv,ffw1,ffw2,c1w,
                                qkvB,ff1B,ff2B,biasB,cwB);
  trans_k<<<512,256,0,stream>>>(dct, dctT);
  convgemm_k<<<1024,256,0,stream>>>(dctT, cwB, c1b, qt, tbuf);
  gemm_k<128,EPI_F32,ASRC_B16,BSRC_F32><<<dim3(1024,1),256,0,stream>>>(
      tbuf, nullptr,nullptr,nullptr,nullptr,nullptr,
      c2w, nullptr, c2b, nullptr, x, nullptr, T_TOK,128,64, 1, nullptr,nullptr);

  for (int l=0;l<4;l++){
    stats_k<<<32768,256,0,stream>>>(x, nullptr, st);
    qkv_k<<<1024,256,0,stream>>>(x, st, ln1g+l*128, ln1b+l*128,
        qkvB + (size_t)l*49152, biasB + l*384, qkv);
    attn_k<<<2048,256,0,stream>>>(qkv, rel+l*196, y2b);
    stats_k<<<32768,256,0,stream>>>(x, y2b, st);
    ff_k<<<1024,256,0,stream>>>(x, y2b, st, ln2g+l*128, ln2b+l*128,
        ff1B + (size_t)l*65536, ff2B + (size_t)l*65536,
        ffb1 + l*512, ffb2 + l*128, x);
  }
  cvt_k<<<16384,256,0,stream>>>(x, xb);
  gemm_k<64,EPI_DEC,ASRC_B16,BSRC_F32><<<dim3(1024,1),256,0,stream>>>(
      xb, nullptr,nullptr,nullptr,nullptr,nullptr,
      decw, nullptr, decb, nullptr, out, nullptr, T_TOK,64,128, 1, qt, dct);
}

// Round 13
// 1230.191 us; speedup vs baseline: 1.1208x; 1.0221x over previous
//
#include <hip/hip_runtime.h>
#include <hip/hip_bf16.h>

typedef __attribute__((ext_vector_type(8))) short short8;
typedef __attribute__((ext_vector_type(4))) float floatx4;
typedef unsigned short u16;
typedef unsigned int u32;

#define T_TOK 131072   // 8 * 128 * 128 tokens
#define LN_EPS 1e-5f
#define ATTN_SCALE 0.08838834764831845f   // 1/sqrt(128)

__device__ __forceinline__ u16 f2b(float f){
  __hip_bfloat16 h = __float2bfloat16(f);
  return *reinterpret_cast<u16*>(&h);
}
__device__ __forceinline__ float blo(u32 u){ union{u32 i; float f;} c; c.i = u<<16; return c.f; }
__device__ __forceinline__ float bhi(u32 u){ union{u32 i; float f;} c; c.i = u & 0xffff0000u; return c.f; }
__device__ __forceinline__ u32 pk2(float lo, float hi){
  return (u32)f2b(lo) | ((u32)f2b(hi)<<16);
}
// Branchless gelu: erf(v/sqrt2) via Abramowitz-Stegun 7.1.26 (max err 1.5e-7,
// far below the bf16 quantization applied right after). ~15 VALU ops.
__device__ __forceinline__ float gelu_f(float v){
  float xs = v * 0.70710678118654752f;
  float ax = fabsf(xs);
  float t = __builtin_amdgcn_rcpf(fmaf(0.3275911f, ax, 1.0f));
  float p = t*fmaf(t, fmaf(t, fmaf(t, fmaf(t, 1.061405429f, -1.453152027f),
                                   1.421413741f), -0.284496736f), 0.254829592f);
  float e = __expf(-ax*ax);
  float er = fmaf(-p, e, 1.0f);
  er = copysignf(er, v);
  return 0.5f*v*(1.0f + er);
}

// ---------------------------------------------------------------------------
// NCHW f32 -> [T,64] bf16 transpose
// ---------------------------------------------------------------------------
__global__ __launch_bounds__(256) void trans_k(
    const float* __restrict__ dct, u16* __restrict__ dctT)
{
  __shared__ u16 tl[256][66];
  int tid = threadIdx.x;
  int p = blockIdx.x*256 + tid;
  int n = p >> 14;
  int r = p & 16383;
  const float* dctn = dct + (long)n*64*16384;
  #pragma unroll
  for (int c=0;c<64;c++) tl[tid][c] = f2b(dctn[c*16384 + r]);
  __syncthreads();
  long base = (long)blockIdx.x*256*64;
  for (int pass=0; pass<64; pass++){
    int idx = pass*256 + tid;
    int pp = idx>>6, o = idx&63;
    dctT[base + idx] = tl[pp][o];
  }
}

// ---------------------------------------------------------------------------
// Encoder conv as MFMA GEMM, v2. Block = one image row (128 px) x 64 out ch.
// Halo rows staged once in XOR-swizzled LDS; weights prepacked fragment-order.
// ---------------------------------------------------------------------------
__global__ __launch_bounds__(256) void convgemm_k(
    const u16* __restrict__ dctT, const uint4* __restrict__ cwB,
    const float* __restrict__ c1b, const float* __restrict__ qt,
    u16* __restrict__ tbuf)
{
  __shared__ uint4 AL[3120];   // [3 rows][130 pxs][8 slots], slot = k8 ^ (pxs&7)
  int tid = threadIdx.x, wave = tid>>6, lane = tid&63;
  int l15 = lane & 15, quad = lane >> 4;
  int bm = blockIdx.x*128;
  int n = bm >> 14;
  int yb = (bm & 16383) >> 7;
  int wm = wave*32;
  for (int i = tid; i < 3120; i += 256){
    int row = i / 1040;
    int rem = i - row*1040;
    int pxs = rem >> 3;
    int k8 = rem & 7;
    int grow = yb + row - 1;
    int gpx = pxs - 1;
    uint4 v = {0,0,0,0};
    if (((unsigned)grow < 128u) && ((unsigned)gpx < 128u))
      v = *reinterpret_cast<const uint4*>(dctT + ((long)bm + (row-1)*128 + gpx)*64 + k8*8);
    AL[row*1040 + (pxs<<3) + (k8 ^ (pxs&7))] = v;
  }
  float qv[4], bi4[4];
  #pragma unroll
  for (int nt=0; nt<4; nt++){
    int col = nt*16 + l15;
    bi4[nt] = c1b[col];
    qv[nt] = qt[n*64 + col];
  }
  uint4 bcur[8];
  #pragma unroll
  for (int i=0;i<8;i++) bcur[i] = cwB[i*64 + lane];

  floatx4 acc[2][4];
  #pragma unroll
  for (int i=0;i<2;i++)
    #pragma unroll
    for (int j=0;j<4;j++)
      #pragma unroll
      for (int e=0;e<4;e++) acc[i][j][e]=0.f;

  __syncthreads();

  #pragma unroll
  for (int tap=0; tap<9; tap++){
    int dy = tap/3 - 1, dx = tap%3 - 1;
    uint4 bnx[8];
    if (tap < 8){
      #pragma unroll
      for (int i=0;i<8;i++) bnx[i] = cwB[(tap+1)*512 + i*64 + lane];
    }
    short8 af[2][2];
    #pragma unroll
    for (int mt=0; mt<2; mt++)
      #pragma unroll
      for (int ks=0; ks<2; ks++){
        int pxs = wm + mt*16 + l15 + dx + 1;
        int k8 = ks*4 + quad;
        af[mt][ks] = *reinterpret_cast<const short8*>(
            &AL[(dy+1)*1040 + (pxs<<3) + (k8 ^ (pxs&7))]);
      }
    #pragma unroll
    for (int ks=0; ks<2; ks++)
      #pragma unroll
      for (int mt=0; mt<2; mt++)
        #pragma unroll
        for (int nt=0; nt<4; nt++)
          acc[mt][nt] = __builtin_amdgcn_mfma_f32_16x16x32_bf16(
              af[mt][ks],
              *reinterpret_cast<const short8*>(&bcur[nt*2+ks]),
              acc[mt][nt], 0,0,0);
    #pragma unroll
    for (int i=0;i<8;i++) bcur[i] = bnx[i];
  }
  const u16* ALu = (const u16*)AL;
  #pragma unroll
  for (int mt=0; mt<2; mt++){
    #pragma unroll
    for (int nt=0; nt<4; nt++){
      int col = nt*16 + l15;
      int k8c = col>>3, sub = col&7;
      #pragma unroll
      for (int rr2=0; rr2<4; rr2++){
        int p = wm + mt*16 + quad*4 + rr2;
        int pxs = p + 1;
        float cen = blo((u32)ALu[(((130 + pxs)<<3) + (k8c ^ (pxs&7)))*8 + sub]);
        float val = acc[mt][nt][rr2] + bi4[nt];
        tbuf[((long)bm + p)*64 + col] = f2b(cen + qv[nt]*val);
      }
    }
  }
}

// ---------------------------------------------------------------------------
// Weight prepack: qkv/ff1/ff2 -> bf16 [n][k]; qkv bias concat (f32);
// conv weights -> bf16 fragment-order [tap][512 uint4-slots].
// ---------------------------------------------------------------------------
__global__ __launch_bounds__(256) void prep_k(
    const float* __restrict__ qw, const float* __restrict__ kw,
    const float* __restrict__ vw, const float* __restrict__ qb2,
    const float* __restrict__ kb2, const float* __restrict__ vb2,
    const float* __restrict__ f1, const float* __restrict__ f2,
    const float* __restrict__ c1w,
    u16* __restrict__ qkvB, u16* __restrict__ ff1B,
    u16* __restrict__ ff2B, float* __restrict__ biasB,
    uint4* __restrict__ cwB)
{
  int idx = blockIdx.x*256 + threadIdx.x;
  if (idx < 196608){
    int l = idx / 49152, r = idx % 49152;
    int sel = r / 16384, rr = r % 16384;
    int k = rr >> 7, nn = rr & 127;
    const float* src = (sel==0? qw : sel==1? kw : vw) + l*16384 + rr;
    qkvB[(size_t)l*49152 + (size_t)(sel*128 + nn)*128 + k] = f2b(*src);
  } else if (idx < 458752){
    int e = idx - 196608; int l = e >> 16, r = e & 65535;
    int k = r >> 9, nn = r & 511;
    ff1B[(size_t)l*65536 + (size_t)nn*128 + k] = f2b(f1[(size_t)l*65536 + r]);
  } else if (idx < 720896){
    int e = idx - 458752; int l = e >> 16, r = e & 65535;
    int k = r >> 7, nn = r & 127;
    ff2B[(size_t)l*65536 + (size_t)nn*512 + k] = f2b(f2[(size_t)l*65536 + r]);
  } else if (idx < 722432){
    int e = idx - 720896;       // [4][384]
    int l = e / 384, c = e % 384;
    int sel = c >> 7, nn = c & 127;
    const float* src = (sel==0? qb2 : sel==1? kb2 : vb2) + l*128 + nn;
    biasB[e] = *src;
  } else if (idx < 727040){
    int e = idx - 722432;       // [9 taps][512 slots]
    int s = e & 511;
    int tap = e >> 9;
    int fn = s>>7, rr = s&127, fk2 = rr>>6, t = rr&63, q = t>>4, nr = t&15;
    int nn = fn*16+nr, k8 = fk2*4+q;
    const float* wp = c1w + nn*576 + k8*72 + tap;
    uint4 pk;
    pk.x = (u32)f2b(wp[0])  | ((u32)f2b(wp[9]) <<16);
    pk.y = (u32)f2b(wp[18]) | ((u32)f2b(wp[27])<<16);
    pk.z = (u32)f2b(wp[36]) | ((u32)f2b(wp[45])<<16);
    pk.w = (u32)f2b(wp[54]) | ((u32)f2b(wp[63])<<16);
    cwB[e] = pk;
  }
}

// ---------------------------------------------------------------------------
// Per-token LN stats (mean, rstd) of x [+ optional bf16 y2]. One wave/token.
// ---------------------------------------------------------------------------
__global__ __launch_bounds__(256) void stats_k(
    const float* __restrict__ x, const u16* __restrict__ yb,
    float* __restrict__ st)
{
  int wave = threadIdx.x>>6, lane = threadIdx.x&63;
  long t = (long)blockIdx.x*4 + wave;
  long idx = t*128 + lane*2;
  float2 vv = *reinterpret_cast<const float2*>(x+idx);
  if (yb){
    u32 p = *reinterpret_cast<const u32*>(yb+idx);
    vv.x += blo(p); vv.y += bhi(p);
  }
  float s = vv.x+vv.y, sq = vv.x*vv.x + vv.y*vv.y;
  #pragma unroll
  for (int o2=32;o2;o2>>=1){ s += __shfl_xor(s,o2); sq += __shfl_xor(sq,o2); }
  float mean = s*(1.f/128.f);
  float var = sq*(1.f/128.f) - mean*mean;
  if (lane==0){
    float2 ms; ms.x = mean; ms.y = rsqrtf(var + LN_EPS);
    *reinterpret_cast<float2*>(st + t*2) = ms;
  }
}

// ---------------------------------------------------------------------------
// QKV projection: block = 128 rows. A = LN1(x) staged ONCE (K=128, 32 KB),
// then 3 output chunks of 128 cols with B-frags loaded direct from L2-hot
// prepacked qkvB (no B LDS, no A re-read, no LN recompute).
// ---------------------------------------------------------------------------
__global__ __launch_bounds__(256,2) void qkv_k(
    const float* __restrict__ x, const float* __restrict__ st,
    const float* __restrict__ lng, const float* __restrict__ lnb,
    const u16* __restrict__ B16, const float* __restrict__ bias,
    u16* __restrict__ qkv)
{
  __shared__ uint4 As[2048];
  int tid = threadIdx.x, wave = tid>>6, lane = tid&63;
  int l15 = lane&15, quad = lane>>4;
  int bm = blockIdx.x*128;
  int wm = (wave>>1)*64, wn = (wave&1)*64;
  int wmf = wm>>4;
  #pragma unroll
  for (int pS=0; pS<8; pS++){
    int s = pS*256 + tid;
    int kh = s>>10, rem = s&1023;
    int fm = rem>>7, rr = rem&127, fk2 = rr>>6, t = rr&63, q2 = t>>4, mr = t&15;
    int m = fm*16+mr;
    int kk = kh*64 + (fk2*4+q2)*8;
    long row = bm + m;
    const float* xp = x + row*128 + kk;
    float4 a = *reinterpret_cast<const float4*>(xp);
    float4 b4 = *reinterpret_cast<const float4*>(xp+4);
    float v[8] = {a.x,a.y,a.z,a.w,b4.x,b4.y,b4.z,b4.w};
    float2 ms = *reinterpret_cast<const float2*>(st + row*2);
    #pragma unroll
    for (int j=0;j<8;j++) v[j] = (v[j]-ms.x)*ms.y*lng[kk+j] + lnb[kk+j];
    uint4 pk;
    pk.x = pk2(v[0],v[1]); pk.y = pk2(v[2],v[3]);
    pk.z = pk2(v[4],v[5]); pk.w = pk2(v[6],v[7]);
    As[s] = pk;
  }
  __syncthreads();
  #pragma unroll 1
  for (int nb=0; nb<3; nb++){
    floatx4 acc[4][4];
    #pragma unroll
    for (int i=0;i<4;i++)
      #pragma unroll
      for (int j=0;j<4;j++)
        #pragma unroll
        for (int e=0;e<4;e++) acc[i][j][e]=0.f;
    #pragma unroll
    for (int kh=0; kh<2; kh++)
      #pragma unroll
      for (int ks=0; ks<2; ks++){
        short8 af[4], bf[4];
        #pragma unroll
        for (int mt=0; mt<4; mt++)
          af[mt] = *reinterpret_cast<const short8*>(&As[kh*1024 + ((wmf+mt)*2+ks)*64 + lane]);
        #pragma unroll
        for (int nt=0; nt<4; nt++)
          bf[nt] = *reinterpret_cast<const short8*>(
              B16 + (nb*128 + wn + nt*16 + l15)*128 + kh*64 + (ks*4+quad)*8);
        #pragma unroll
        for (int mt=0;mt<4;mt++)
          #pragma unroll
          for (int nt=0;nt<4;nt++)
            acc[mt][nt] = __builtin_amdgcn_mfma_f32_16x16x32_bf16(af[mt], bf[nt], acc[mt][nt], 0,0,0);
      }
    #pragma unroll
    for (int nt=0;nt<4;nt++){
      int col = nb*128 + wn + nt*16 + l15;
      float bi = bias[col];
      #pragma unroll
      for (int mt=0;mt<4;mt++){
        int row0 = bm + wm + mt*16 + quad*4;
        #pragma unroll
        for (int r=0;r<4;r++)
          qkv[(long)(row0+r)*384 + col] = f2b(acc[mt][nt][r] + bi);
      }
    }
  }
}

// ---------------------------------------------------------------------------
// Fused FeedForward v7: x = y2b + W2 @ gelu(W1 @ LN2(x+y2b) + b1) + b2,
// PLUS fused next-layer LN1 stats: epilogue accumulates per-row sum/sumsq
// of the x it writes (4 vals/thread/row -> 4-step quad shfl_xor -> cross-
// wave combine via dead Hs buffer -> st). Removes 3 stats_k launches + a
// 64 MB x re-read per layer. Block reads st[bm..bm+127] in A-stage and
// overwrites only those rows at the end: no cross-block hazard.
// r10 config otherwise (112 VGPR, 64 KB LDS, 2 blocks/CU -- r11: do NOT
// cap VGPR lower, it spills).
// ---------------------------------------------------------------------------
__global__ __launch_bounds__(256,2) void ff_k(
    const float* __restrict__ x, const u16* __restrict__ y2b,
    const float* __restrict__ st,
    const float* __restrict__ lng, const float* __restrict__ lnb,
    const u16* __restrict__ w1, const u16* __restrict__ w2,
    const float* __restrict__ b1, const float* __restrict__ b2,
    float* __restrict__ xo, float* __restrict__ stO)
{
  __shared__ uint4 As[2048];     // 128 rows x 128 k (fragment-major)
  __shared__ u16 Hs[2][8192];    // [128 rows][64 cols] swizzled, dbuf
  int tid = threadIdx.x, wave = tid>>6, lane = tid&63;
  int l15 = lane&15, quad = lane>>4;
  int bm = blockIdx.x*128;
  int wm = (wave>>1)*64;        // row base (both gemms)
  int wn1 = (wave&1)*32;        // gemm1 col base within 64-col chunk
  int wn2 = (wave&1)*64;        // gemm2 output col base
  int wmf = wm>>4;
  // ---- stage A = LN2(x + y2b), K=128
  #pragma unroll
  for (int pS=0; pS<8; pS++){
    int s = pS*256 + tid;
    int kh = s>>10, rem = s&1023;
    int fm = rem>>7, rr = rem&127, fk2 = rr>>6, t = rr&63, q2 = t>>4, mr = t&15;
    int m = fm*16+mr;
    int kk = kh*64 + (fk2*4+q2)*8;
    long row = bm + m;
    const float* xp = x + row*128 + kk;
    float4 a = *reinterpret_cast<const float4*>(xp);
    float4 b4 = *reinterpret_cast<const float4*>(xp+4);
    float v[8] = {a.x,a.y,a.z,a.w,b4.x,b4.y,b4.z,b4.w};
    uint4 yv = *reinterpret_cast<const uint4*>(y2b + row*128 + kk);
    v[0]+=blo(yv.x); v[1]+=bhi(yv.x); v[2]+=blo(yv.y); v[3]+=bhi(yv.y);
    v[4]+=blo(yv.z); v[5]+=bhi(yv.z); v[6]+=blo(yv.w); v[7]+=bhi(yv.w);
    float2 ms = *reinterpret_cast<const float2*>(st + row*2);
    #pragma unroll
    for (int j=0;j<8;j++) v[j] = (v[j]-ms.x)*ms.y*lng[kk+j] + lnb[kk+j];
    uint4 pk;
    pk.x = pk2(v[0],v[1]); pk.y = pk2(v[2],v[3]);
    pk.z = pk2(v[4],v[5]); pk.w = pk2(v[6],v[7]);
    As[s] = pk;
  }
  __syncthreads();

  floatx4 acc2[4][4];
  #pragma unroll
  for (int i=0;i<4;i++)
    #pragma unroll
    for (int j=0;j<4;j++)
      #pragma unroll
      for (int e=0;e<4;e++) acc2[i][j][e]=0.f;

  // gemm1 of one 64-col chunk -> acc1[4][2] (64 rows x 32 cols per wave)
  auto GEMM1 = [&](int hc, floatx4 (&acc1)[4][2]){
    #pragma unroll
    for (int i=0;i<4;i++)
      #pragma unroll
      for (int j=0;j<2;j++)
        #pragma unroll
        for (int e=0;e<4;e++) acc1[i][j][e]=0.f;
    #pragma unroll
    for (int kh=0; kh<2; kh++)
      #pragma unroll
      for (int ks=0; ks<2; ks++){
        short8 af[4], bf[2];
        #pragma unroll
        for (int mt=0; mt<4; mt++)
          af[mt] = *reinterpret_cast<const short8*>(&As[kh*1024 + ((wmf+mt)*2+ks)*64 + lane]);
        #pragma unroll
        for (int nt=0; nt<2; nt++)
          bf[nt] = *reinterpret_cast<const short8*>(
              w1 + (hc*64 + wn1 + nt*16 + l15)*128 + kh*64 + (ks*4+quad)*8);
        #pragma unroll
        for (int mt=0;mt<4;mt++)
          #pragma unroll
          for (int nt=0;nt<2;nt++)
            acc1[mt][nt] = __builtin_amdgcn_mfma_f32_16x16x32_bf16(af[mt], bf[nt], acc1[mt][nt], 0,0,0);
      }
  };
  // bias+gelu+pack acc1 into Hs[hc&1] (swizzled [128][64])
  auto GELUW = [&](int hc, floatx4 (&acc1)[4][2]){
    float b1v[2];
    #pragma unroll
    for (int nt=0;nt<2;nt++) b1v[nt] = b1[hc*64 + wn1 + nt*16 + l15];
    u16* hb = Hs[hc&1];
    #pragma unroll
    for (int mt=0;mt<4;mt++)
      #pragma unroll
      for (int nt=0;nt<2;nt++){
        int col = wn1 + nt*16 + l15;
        int c8 = col>>3, c7 = col&7;
        #pragma unroll
        for (int r=0;r<4;r++){
          int row = wm + mt*16 + quad*4 + r;
          float val = acc1[mt][nt][r] + b1v[nt];
          hb[(row<<6) + ((c8 ^ (row&7))<<3) + c7] = f2b(gelu_f(val));
        }
      }
  };
  // gemm2 partial over one 64-k chunk
  auto GEMM2 = [&](int hc){
    const u16* hb = Hs[hc&1];
    #pragma unroll
    for (int ks2=0; ks2<2; ks2++){
      short8 af[4], bf[4];
      #pragma unroll
      for (int mt=0;mt<4;mt++){
        int row = wm + mt*16 + l15;
        int col8 = ks2*4 + quad;
        af[mt] = *reinterpret_cast<const short8*>(
            &hb[(row<<6) + ((col8 ^ (row&7))<<3)]);
      }
      #pragma unroll
      for (int nt=0;nt<4;nt++)
        bf[nt] = *reinterpret_cast<const short8*>(
            w2 + (wn2 + nt*16 + l15)*512 + hc*64 + ks2*32 + quad*8);
      #pragma unroll
      for (int mt=0;mt<4;mt++)
        #pragma unroll
        for (int nt=0;nt<4;nt++)
          acc2[mt][nt] = __builtin_amdgcn_mfma_f32_16x16x32_bf16(af[mt], bf[nt], acc2[mt][nt], 0,0,0);
    }
  };

  // ---- pipelined main loop
  {
    floatx4 acc1a[4][2];
    GEMM1(0, acc1a);
    GELUW(0, acc1a);
  }
  __syncthreads();
  #pragma unroll 1
  for (int hc=0; hc<8; hc++){
    floatx4 acc1n[4][2];
    if (hc < 7) GEMM1(hc+1, acc1n);   // independent of GEMM2(hc) below
    GEMM2(hc);
    if (hc < 7){
      GELUW(hc+1, acc1n);
      __syncthreads();
    }
  }
  // ---- epilogue: x = acc2 + b2 + y2b, fused next-layer LN1 stats
  __syncthreads();                 // all GEMM2 reads of Hs done; reuse Hs
  float* red = (float*)Hs;         // [128 local rows][2 halves][s,sq]
  float b2v[4];
  #pragma unroll
  for (int nt=0;nt<4;nt++) b2v[nt] = b2[wn2 + nt*16 + l15];
  #pragma unroll
  for (int mt=0;mt<4;mt++){
    #pragma unroll
    for (int r=0;r<4;r++){
      int lrow = wm + mt*16 + quad*4 + r;
      long row = bm + lrow;
      float s = 0.f, sq = 0.f;
      #pragma unroll
      for (int nt=0;nt<4;nt++){
        int col = wn2 + nt*16 + l15;
        float val = acc2[mt][nt][r] + b2v[nt] + blo((u32)y2b[row*128 + col]);
        xo[row*128 + col] = val;
        s += val; sq += val*val;
      }
      #pragma unroll
      for (int o=1;o<16;o<<=1){ s += __shfl_xor(s,o); sq += __shfl_xor(sq,o); }
      if (l15 == 0){
        red[lrow*4 + (wave&1)*2]     = s;
        red[lrow*4 + (wave&1)*2 + 1] = sq;
      }
    }
  }
  __syncthreads();
  if (tid < 128){
    float s  = red[tid*4]   + red[tid*4+2];
    float sq = red[tid*4+1] + red[tid*4+3];
    float mean = s*(1.f/128.f);
    float var  = sq*(1.f/128.f) - mean*mean;
    float2 ms; ms.x = mean; ms.y = rsqrtf(var + LN_EPS);
    *reinterpret_cast<float2*>(stO + (long)(bm + tid)*2) = ms;
  }
}

// ---------------------------------------------------------------------------
// MFMA bf16 GEMM (encoder c2 + decoder only now).
// ---------------------------------------------------------------------------
constexpr int EPI_F32 = 0;
constexpr int EPI_DEC = 4;
constexpr int ASRC_B16 = 0;
constexpr int BSRC_F32 = 0;

template<int BN, int EPI, int ASRC, int BSRC>
__global__ __launch_bounds__(256) void gemm_k(
    const u16* __restrict__ A16, const float* __restrict__ Axf,
    const u16* __restrict__ Yadd, const float* __restrict__ st,
    const float* __restrict__ lng, const float* __restrict__ lnb,
    const float* __restrict__ Bsrc, const u16* __restrict__ B16,
    const float* __restrict__ bias, const u16* __restrict__ resid,
    float* __restrict__ outF, u16* __restrict__ outB,
    int M, int N, int K, int bNK,
    const float* __restrict__ qtp, const float* __restrict__ dctp)
{
  static_assert(BN==128 || BN==64, "BN");
  constexpr int MF = (BN==128)?4:2;
  constexpr int BSLOT = (BN/16)*128;
  __shared__ uint4 As[1024];
  __shared__ uint4 Bs[BSLOT];
  int tid = threadIdx.x;
  int wave = tid>>6, lane = tid&63;
  int bm = blockIdx.x * 128;
  int bn = blockIdx.y * BN;
  int wm = (BN==128)? (wave>>1)*64 : wave*32;
  int wn = (BN==128)? (wave&1)*64 : 0;
  int wmf = wm>>4, wnf = wn>>4;
  floatx4 acc[MF][4];
  #pragma unroll
  for (int i=0;i<MF;i++)
    #pragma unroll
    for (int j=0;j<4;j++)
      #pragma unroll
      for (int e=0;e<4;e++) acc[i][j][e]=0.f;

  for (int k0=0; k0<K; k0+=64){
    __syncthreads();
    #pragma unroll
    for (int pS=0; pS<4; pS++){
      int s = pS*256 + tid;
      int fm = s>>7, rr = s&127, fk2 = rr>>6, t = rr&63, quad = t>>4, mr = t&15;
      int m = fm*16+mr, k8 = fk2*4+quad;
      int kk = k0 + k8*8;
      long row = bm + m;
      As[s] = *reinterpret_cast<const uint4*>(A16 + row*K + kk);
    }
    #pragma unroll
    for (int pS=0; pS<BSLOT/256; pS++){
      int s = pS*256 + tid;
      int fn = s>>7, rr = s&127, fk2 = rr>>6, t = rr&63, quad = t>>4, nr = t&15;
      int nn = fn*16+nr, k8 = fk2*4+quad;
      int kk = k0 + k8*8;
      float v[8];
      if (bNK){
        const float* src = Bsrc + (long)(bn+nn)*K + kk;
        float4 a = *reinterpret_cast<const float4*>(src);
        float4 b = *reinterpret_cast<const float4*>(src+4);
        v[0]=a.x; v[1]=a.y; v[2]=a.z; v[3]=a.w; v[4]=b.x; v[5]=b.y; v[6]=b.z; v[7]=b.w;
      } else {
        #pragma unroll
        for (int j=0;j<8;j++) v[j] = Bsrc[(long)(kk+j)*N + bn + nn];
      }
      uint4 pk;
      pk.x = pk2(v[0],v[1]); pk.y = pk2(v[2],v[3]);
      pk.z = pk2(v[4],v[5]); pk.w = pk2(v[6],v[7]);
      Bs[s] = pk;
    }
    __syncthreads();
    #pragma unroll
    for (int ks=0; ks<2; ks++){
      short8 af[MF], bfr[4];
      #pragma unroll
      for (int mt=0; mt<MF; mt++)
        af[mt] = *reinterpret_cast<const short8*>(&As[((wmf+mt)*2+ks)*64 + lane]);
      #pragma unroll
      for (int nt=0; nt<4; nt++)
        bfr[nt] = *reinterpret_cast<const short8*>(&Bs[((wnf+nt)*2+ks)*64 + lane]);
      #pragma unroll
      for (int mt=0; mt<MF; mt++)
        #pragma unroll
        for (int nt=0; nt<4; nt++)
          acc[mt][nt] = __builtin_amdgcn_mfma_f32_16x16x32_bf16(af[mt], bfr[nt], acc[mt][nt], 0,0,0);
    }
  }
  #pragma unroll
  for (int mt=0; mt<MF; mt++){
    #pragma unroll
    for (int nt=0; nt<4; nt++){
      int col = bn + wn + nt*16 + (lane&15);
      int row0 = bm + wm + mt*16 + ((lane>>4)<<2);
      float bi = bias[col];
      #pragma unroll
      for (int rr2=0; rr2<4; rr2++){
        long row = row0 + rr2;
        float val = acc[mt][nt][rr2] + bi;
        if constexpr (EPI==EPI_F32){
          outF[row*N + col] = val;
        } else {
          int nn2 = (int)(row>>14), rm = (int)(row&16383);
          long didx = ((long)(nn2*64 + col)<<14) + rm;
          outF[didx] = dctp[didx] + val*qtp[nn2*64+col];
        }
      }
    }
  }
}

// ---------------------------------------------------------------------------
// MFMA local attention (v2, unchanged from r2 passing version).
// ---------------------------------------------------------------------------
__global__ __launch_bounds__(256) void attn_k(
    const u16* __restrict__ qkv, const float* __restrict__ rb,
    u16* __restrict__ y2b)
{
  __shared__ __align__(16) char lds_all[4*7168];
  int tid = threadIdx.x, wave = tid>>6, lane = tid&63;
  int l15 = lane & 15, quad = lane >> 4;
  char* wl = lds_all + wave*7168;
  u16* Kl = (u16*)wl;              // [32 px][40 u16]
  u16* Vt = (u16*)(wl + 2560);     // [32 ch][40 u16]
  float* ebl = (float*)(wl + 5120);// [23][21] masked exp(bias)
  int bi = blockIdx.x;
  int n = bi >> 8, t2 = bi & 255;
  int ty = (t2 >> 4) << 3, tx = (t2 & 15) << 3;
  int hh = wave;
  for (int k = lane; k < 512; k += 64){
    int dyp = k / 21, dxp = k - dyp*21;
    int dy = dyp - 7, dx = dxp - 7;
    float v = 0.f;
    if (((unsigned)dy < 7u) && ((unsigned)dx < 7u))
      v = __expf(rb[hh*49 + dy*7 + dx]);
    ebl[k] = v;
  }
  short8 qf[4];
  #pragma unroll
  for (int mt=0; mt<4; mt++){
    int m = mt*16 + l15;
    long tq = (long)n*16384 + (long)(ty + (m>>3))*128 + (tx + (m&7));
    qf[mt] = *reinterpret_cast<const short8*>(qkv + tq*384 + hh*32 + quad*8);
  }
  int pxs[2], c8s[2];
  #pragma unroll
  for (int ps=0; ps<2; ps++){
    int s = ps*64 + lane;
    pxs[ps] = s >> 2; c8s[ps] = s & 3;
  }
  auto load_chunk = [&](int c, uint4* krr, uint4* vrr){
    #pragma unroll
    for (int ps=0; ps<2; ps++){
      int hp = c*32 + pxs[ps];
      int hy = hp / 14, hx = hp % 14;
      int gy = ty + hy - 3, gx = tx + hx - 3;
      uint4 kz = {0,0,0,0}, vz = {0,0,0,0};
      if (((unsigned)gy < 128u) && ((unsigned)gx < 128u)){
        long t = (long)n*16384 + gy*128 + gx;
        const u16* p = qkv + t*384 + hh*32 + c8s[ps]*8;
        kz = *reinterpret_cast<const uint4*>(p + 128);
        vz = *reinterpret_cast<const uint4*>(p + 256);
      }
      krr[ps] = kz; vrr[ps] = vz;
    }
  };
  uint4 kr[2], vr[2];
  load_chunk(0, kr, vr);

  floatx4 oacc[4][2];
  float lsum[4];
  #pragma unroll
  for (int mt=0;mt<4;mt++){
    lsum[mt] = 0.f;
    #pragma unroll
    for (int nf=0;nf<2;nf++)
      #pragma unroll
      for (int e=0;e<4;e++) oacc[mt][nf][e]=0.f;
  }
  int qb0 = (l15>>3)*21 + (l15&7);
  bool lower = (lane < 32);
  bool sendRecv = (quad==0) || (quad==3);
  bool qodd = (quad & 1) != 0;
  bool q0q = (quad==0), q1q = (quad==1);

  for (int c=0; c<7; c++){
    #pragma unroll
    for (int ps=0; ps<2; ps++){
      *reinterpret_cast<uint4*>(Kl + pxs[ps]*40 + c8s[ps]*8) = kr[ps];
      u32 wv[4] = {vr[ps].x, vr[ps].y, vr[ps].z, vr[ps].w};
      #pragma unroll
      for (int i=0;i<8;i++){
        u16 val = (u16)((wv[i>>1] >> ((i&1)*16)) & 0xffffu);
        Vt[(c8s[ps]*8 + i)*40 + pxs[ps]] = val;
      }
    }
    uint4 kr2[2], vr2[2];
    if (c < 6) load_chunk(c+1, kr2, vr2);
    short8 kf0 = *reinterpret_cast<const short8*>(Kl + l15*40 + quad*8);
    short8 kf1 = *reinterpret_cast<const short8*>(Kl + (16 + l15)*40 + quad*8);
    short8 vf0 = *reinterpret_cast<const short8*>(Vt + l15*40 + quad*8);
    short8 vf1 = *reinterpret_cast<const short8*>(Vt + (16 + l15)*40 + quad*8);
    int hb[2][4];
    #pragma unroll
    for (int nf=0;nf<2;nf++)
      #pragma unroll
      for (int r=0;r<4;r++){
        int hp = c*32 + nf*16 + quad*4 + r;
        int hy = hp / 14, hx = hp - hy*14;
        hb[nf][r] = hy*21 + hx + 154;
      }
    #pragma unroll
    for (int mt=0;mt<4;mt++){
      floatx4 zz; zz[0]=0.f; zz[1]=0.f; zz[2]=0.f; zz[3]=0.f;
      floatx4 s0 = __builtin_amdgcn_mfma_f32_16x16x32_bf16(kf0, qf[mt], zz, 0,0,0);
      floatx4 s1 = __builtin_amdgcn_mfma_f32_16x16x32_bf16(kf1, qf[mt], zz, 0,0,0);
      int qb = qb0 + mt*42;
      float p0[4], p1[4];
      #pragma unroll
      for (int r=0;r<4;r++){
        p0[r] = __expf(s0[r]*ATTN_SCALE) * ebl[hb[0][r] - qb];
        p1[r] = __expf(s1[r]*ATTN_SCALE) * ebl[hb[1][r] - qb];
      }
      lsum[mt] += ((p0[0]+p0[1]) + (p0[2]+p0[3])) + ((p1[0]+p1[1]) + (p1[2]+p1[3]));
      u32 Aw = pk2(p0[0], p0[1]);
      u32 Bw = pk2(p0[2], p0[3]);
      u32 Cw = pk2(p1[0], p1[1]);
      u32 Dw = pk2(p1[2], p1[3]);
      u32 own0 = lower ? Aw : Cw;
      u32 own1 = lower ? Bw : Dw;
      u32 recv1 = (u32)__shfl_xor((int)(lower ? Cw : Aw), 32);
      u32 recv2 = (u32)__shfl_xor((int)(lower ? Dw : Bw), 32);
      u32 r3 = (u32)__shfl_xor((int)(sendRecv ? recv1 : own0), 16);
      u32 r4 = (u32)__shfl_xor((int)(sendRecv ? recv2 : own1), 16);
      uint4 paw;
      paw.x = qodd ? r3 : (q0q ? own0 : recv1);
      paw.y = qodd ? r4 : (q0q ? own1 : recv2);
      paw.z = qodd ? (q1q ? recv1 : own0) : r3;
      paw.w = qodd ? (q1q ? recv2 : own1) : r4;
      short8 pa = *reinterpret_cast<const short8*>(&paw);
      oacc[mt][0] = __builtin_amdgcn_mfma_f32_16x16x32_bf16(pa, vf0, oacc[mt][0], 0,0,0);
      oacc[mt][1] = __builtin_amdgcn_mfma_f32_16x16x32_bf16(pa, vf1, oacc[mt][1], 0,0,0);
    }
    #pragma unroll
    for (int ps=0; ps<2; ps++){ kr[ps]=kr2[ps]; vr[ps]=vr2[ps]; }
  }
  float rinv[4];
  #pragma unroll
  for (int mt=0;mt<4;mt++){
    float s = lsum[mt];
    s += __shfl_xor(s, 16);
    s += __shfl_xor(s, 32);
    rinv[mt] = 1.0f / s;
  }
  #pragma unroll
  for (int mt=0;mt<4;mt++){
    #pragma unroll
    for (int r=0;r<4;r++){
      int row = mt*16 + quad*4 + r;
      float sc = __shfl(rinv[mt], (quad<<2) | r);
      long t = (long)n*16384 + (long)(ty + (row>>3))*128 + (tx + (row&7));
      #pragma unroll
      for (int nfv=0;nfv<2;nfv++)
        y2b[t*128 + hh*32 + nfv*16 + l15] = f2b(oacc[mt][nfv][r] * sc);
    }
  }
}

__global__ __launch_bounds__(256) void cvt_k(const float* __restrict__ x, u16* __restrict__ o){
  long i = ((long)blockIdx.x*256 + threadIdx.x)*4;
  float4 vv = *reinterpret_cast<const float4*>(x+i);
  uint2 pk;
  pk.x = (u32)f2b(vv.x) | ((u32)f2b(vv.y)<<16);
  pk.y = (u32)f2b(vv.z) | ((u32)f2b(vv.w)<<16);
  *reinterpret_cast<uint2*>(o+i) = pk;
}

// ---------------------------------------------------------------------------
extern "C" void kernel_launch(void* const* d_in, const int* in_sizes, int n_in,
                              void* d_out, int out_size, void* d_ws, size_t ws_size,
                              hipStream_t stream)
{
  (void)in_sizes; (void)n_in; (void)out_size; (void)ws_size;
  const float* dct  = (const float*)d_in[0];
  const float* qt   = (const float*)d_in[1];
  const float* c1w  = (const float*)d_in[2];
  const float* c1b  = (const float*)d_in[3];
  const float* c2w  = (const float*)d_in[4];
  const float* c2b  = (const float*)d_in[5];
  const float* ln1g = (const float*)d_in[6];
  const float* ln1b = (const float*)d_in[7];
  const float* qw   = (const float*)d_in[8];
  const float* qbv  = (const float*)d_in[9];
  const float* kw   = (const float*)d_in[10];
  const float* kbv  = (const float*)d_in[11];
  const float* vw   = (const float*)d_in[12];
  const float* vbv  = (const float*)d_in[13];
  const float* rel  = (const float*)d_in[14];
  const float* ln2g = (const float*)d_in[15];
  const float* ln2b = (const float*)d_in[16];
  const float* ffw1 = (const float*)d_in[17];
  const float* ffb1 = (const float*)d_in[18];
  const float* ffw2 = (const float*)d_in[19];
  const float* ffb2 = (const float*)d_in[20];
  const float* decw = (const float*)d_in[21];
  const float* decb = (const float*)d_in[22];
  float* out = (float*)d_out;

  char* w = (char*)d_ws;
  float* x    = (float*)w;                          // 64 MB  [0, 64M)
  float* st   = (float*)(w + 67108864);             //  1 MB
  u16*  qkv   = (u16*)(w + 68157440);               // 96 MB  [T,384]
  u16*  y2b   = (u16*)(w + 168820736);              // 32 MB  [T,128]
  u16*  qkvB  = (u16*)(w + 202375168);              // 384 KB  packed qkv w
  u16*  ff1B  = (u16*)(w + 202768384);              // 512 KB
  u16*  ff2B  = (u16*)(w + 203292672);              // 512 KB
  float* biasB= (float*)(w + 203816960);            //   6 KB
  uint4* cwB  = (uint4*)(w + 203823104);            //  72 KB packed conv w
  u16*  tbuf = y2b;       // alias: encoder FiLM out (16 MB)
  u16*  dctT = qkv;       // alias: transposed dct (16 MB), dead before qkv gemm
  u16*  xb   = y2b;       // alias: decoder bf16 x

  prep_k<<<2840,256,0,stream>>>(qw,kw,vw,qbv,kbv,vbv,ffw1,ffw2,c1w,
                                qkvB,ff1B,ff2B,biasB,cwB);
  trans_k<<<512,256,0,stream>>>(dct, dctT);
  convgemm_k<<<1024,256,0,stream>>>(dctT, cwB, c1b, qt, tbuf);
  gemm_k<128,EPI_F32,ASRC_B16,BSRC_F32><<<dim3(1024,1),256,0,stream>>>(
      tbuf, nullptr,nullptr,nullptr,nullptr,nullptr,
      c2w, nullptr, c2b, nullptr, x, nullptr, T_TOK,128,64, 1, nullptr,nullptr);

  stats_k<<<32768,256,0,stream>>>(x, nullptr, st);   // LN1 stats for l=0
  for (int l=0;l<4;l++){
    qkv_k<<<1024,256,0,stream>>>(x, st, ln1g+l*128, ln1b+l*128,
        qkvB + (size_t)l*49152, biasB + l*384, qkv);
    attn_k<<<2048,256,0,stream>>>(qkv, rel+l*196, y2b);
    stats_k<<<32768,256,0,stream>>>(x, y2b, st);     // LN2 stats
    ff_k<<<1024,256,0,stream>>>(x, y2b, st, ln2g+l*128, ln2b+l*128,
        ff1B + (size_t)l*65536, ff2B + (size_t)l*65536,
        ffb1 + l*512, ffb2 + l*128, x, st);          // writes x + next LN1 stats
  }
  cvt_k<<<16384,256,0,stream>>>(x, xb);
  gemm_k<64,EPI_DEC,ASRC_B16,BSRC_F32><<<dim3(1024,1),256,0,stream>>>(
      xb, nullptr,nullptr,nullptr,nullptr,nullptr,
      decw, nullptr, decb, nullptr, out, nullptr, T_TOK,64,128, 1, qt, dct);
}